// Round 10
// baseline (559.580 us; speedup 1.0000x reference)
//
#include <hip/hip_runtime.h>
#include <cstdio>
#include <cstdint>

// ---------------------------------------------------------------------------
// GADGNN forward. R10: gemm34 v3 (36 KB LDS, 4 blocks/CU via two half-K h2
// exchange rounds), gather unroll-2 remainder, merged S1/S4 graph GEMM.
//  - k_gemm12: GEMM1+GEMM2 fused, weights LDS-resident (barrier-free K-loop)
//  - prop() twice; Wcat@W3 and W5@W6 folded; dst-CSR gather (no fp32 atomics)
// ---------------------------------------------------------------------------

typedef unsigned short u16;
typedef __bf16 v8bf __attribute__((ext_vector_type(8)));
typedef float f32x4 __attribute__((ext_vector_type(4)));
typedef u16 u16x8 __attribute__((ext_vector_type(8)));

__device__ inline float b2f(u16 u) {
  union { unsigned int i; float f; } x; x.i = ((unsigned int)u) << 16; return x.f;
}
__device__ inline u16 f2b(float f) {  // RNE
  unsigned int u = __float_as_uint(f);
  unsigned int r = (u + 0x7fffu + ((u >> 16) & 1u)) >> 16;
  return (u16)r;
}

// async global->LDS, 16 B per lane; lds dest = base + lane*16 (wave-uniform base)
__device__ __forceinline__ void glds16(const u16* g, u16* l) {
  __builtin_amdgcn_global_load_lds(
      (const __attribute__((address_space(1))) void*)g,
      (__attribute__((address_space(3))) void*)l, 16, 0, 0);
}

// ---------------- prep kernels ----------------

__global__ void k_hist(const int* __restrict__ dst, int* __restrict__ indeg, int E) {
  int e = blockIdx.x * blockDim.x + threadIdx.x;
  if (e < E) atomicAdd(&indeg[dst[e]], 1);
}

__launch_bounds__(256)
__global__ void k_scan1(const int* __restrict__ indeg, int* __restrict__ rowptr,
                        int* __restrict__ bsum, int N) {
  int b = blockIdx.x, t = threadIdx.x;
  int base = b * 1024 + t * 4;
  int4 v = make_int4(0, 0, 0, 0);
  if (base + 3 < N) v = *(const int4*)(indeg + base);
  else if (base < N) {
    v.x = indeg[base];
    v.y = base + 1 < N ? indeg[base + 1] : 0;
    v.z = base + 2 < N ? indeg[base + 2] : 0;
  }
  int s = v.x + v.y + v.z + v.w;
  int lane = t & 63, w = t >> 6;
  int inc = s;
#pragma unroll
  for (int o = 1; o < 64; o <<= 1) { int u = __shfl_up(inc, o, 64); if (lane >= o) inc += u; }
  __shared__ int wsum[4];
  if (lane == 63) wsum[w] = inc;
  __syncthreads();
  int woff = 0;
#pragma unroll
  for (int i = 0; i < 4; ++i) if (i < w) woff += wsum[i];
  int excl = woff + inc - s;
  int4 o4;
  o4.x = excl; o4.y = o4.x + v.x; o4.z = o4.y + v.y; o4.w = o4.z + v.z;
  if (base + 3 < N) *(int4*)(rowptr + base) = o4;
  else if (base < N) {
    rowptr[base] = o4.x;
    if (base + 1 < N) rowptr[base + 1] = o4.y;
    if (base + 2 < N) rowptr[base + 2] = o4.z;
  }
  if (t == 255) bsum[b] = woff + inc;
}

__launch_bounds__(256)
__global__ void k_scan2(const int* __restrict__ bsum, int* __restrict__ boff, int B) {
  int t = threadIdx.x;
  int v = t < B ? bsum[t] : 0;
  int lane = t & 63, w = t >> 6;
  int inc = v;
#pragma unroll
  for (int o = 1; o < 64; o <<= 1) { int u = __shfl_up(inc, o, 64); if (lane >= o) inc += u; }
  __shared__ int wsum[4];
  if (lane == 63) wsum[w] = inc;
  __syncthreads();
  int woff = 0;
#pragma unroll
  for (int i = 0; i < 4; ++i) if (i < w) woff += wsum[i];
  if (t < B) boff[t] = woff + inc - v;
  if (t == 255) boff[B] = woff + inc;
}

__launch_bounds__(256)
__global__ void k_scan3(int* __restrict__ rowptr, const int* __restrict__ boff,
                        int* __restrict__ rowcur, int N, int B) {
  int b = blockIdx.x, t = threadIdx.x;
  int base = b * 1024 + t * 4;
  int add = boff[b];
  if (base + 3 < N) {
    int4 v = *(const int4*)(rowptr + base);
    v.x += add; v.y += add; v.z += add; v.w += add;
    *(int4*)(rowptr + base) = v;
    *(int4*)(rowcur + base) = v;
  } else if (base < N) {
    for (int i = base; i < N; ++i) { int v = rowptr[i] + add; rowptr[i] = v; rowcur[i] = v; }
  }
  if (b == 0 && t == 0) rowptr[N] = boff[B];
}

// scatter edges into CSR slots + out-degree histogram
__global__ void k_scatter(const int* __restrict__ src, const int* __restrict__ dst,
                          int* __restrict__ rowcur, int* __restrict__ deg,
                          int* __restrict__ csre, int E) {
  int e = blockIdx.x * blockDim.x + threadIdx.x;
  if (e >= E) return;
  int s = src[e];
  atomicAdd(&deg[s], 1);
  int p = atomicAdd(&rowcur[dst[e]], 1);
  csre[p] = s;
}

// out[d,:] = (-scale*dis[d]) * sum_e dis[s_e]*x[s_e,:]  (- sub[d,:] if sub)
__launch_bounds__(256)
__global__ void k_gather(const u16* __restrict__ x, const int* __restrict__ rowptr,
                         const int* __restrict__ csre, const float* __restrict__ dis,
                         const u16* __restrict__ sub, float scale,
                         u16* __restrict__ out, int N) {
  int node = blockIdx.x * 4 + (threadIdx.x >> 6);
  if (node >= N) return;
  int lane = threadIdx.x & 63;
  int fo = lane * 2;
  int b = rowptr[node], e = rowptr[node + 1];
  float a0 = 0.f, a1 = 0.f;
  int i = b;
  for (; i + 4 <= e; i += 4) {
    int s0 = csre[i], s1 = csre[i + 1], s2 = csre[i + 2], s3 = csre[i + 3];
    unsigned v0 = *(const unsigned*)(x + (size_t)s0 * 128 + fo);
    unsigned v1 = *(const unsigned*)(x + (size_t)s1 * 128 + fo);
    unsigned v2 = *(const unsigned*)(x + (size_t)s2 * 128 + fo);
    unsigned v3 = *(const unsigned*)(x + (size_t)s3 * 128 + fo);
    float w0 = dis[s0], w1 = dis[s1], w2 = dis[s2], w3 = dis[s3];
    a0 = fmaf(w0, b2f((u16)(v0 & 0xffff)), a0); a1 = fmaf(w0, b2f((u16)(v0 >> 16)), a1);
    a0 = fmaf(w1, b2f((u16)(v1 & 0xffff)), a0); a1 = fmaf(w1, b2f((u16)(v1 >> 16)), a1);
    a0 = fmaf(w2, b2f((u16)(v2 & 0xffff)), a0); a1 = fmaf(w2, b2f((u16)(v2 >> 16)), a1);
    a0 = fmaf(w3, b2f((u16)(v3 & 0xffff)), a0); a1 = fmaf(w3, b2f((u16)(v3 >> 16)), a1);
  }
  for (; i + 2 <= e; i += 2) {  // paired remainder: 2 independent row loads
    int s0 = csre[i], s1 = csre[i + 1];
    unsigned v0 = *(const unsigned*)(x + (size_t)s0 * 128 + fo);
    unsigned v1 = *(const unsigned*)(x + (size_t)s1 * 128 + fo);
    float w0 = dis[s0], w1 = dis[s1];
    a0 = fmaf(w0, b2f((u16)(v0 & 0xffff)), a0); a1 = fmaf(w0, b2f((u16)(v0 >> 16)), a1);
    a0 = fmaf(w1, b2f((u16)(v1 & 0xffff)), a0); a1 = fmaf(w1, b2f((u16)(v1 >> 16)), a1);
  }
  if (i < e) {
    int s = csre[i];
    float w = dis[s];
    unsigned v = *(const unsigned*)(x + (size_t)s * 128 + fo);
    a0 = fmaf(w, b2f((u16)(v & 0xffff)), a0);
    a1 = fmaf(w, b2f((u16)(v >> 16)), a1);
  }
  float m = -scale * dis[node];
  a0 *= m; a1 *= m;
  if (sub) {
    unsigned v = *(const unsigned*)(sub + (size_t)node * 128 + fo);
    a0 -= b2f((u16)(v & 0xffff));
    a1 -= b2f((u16)(v >> 16));
  }
  unsigned o = (unsigned)f2b(a0) | ((unsigned)f2b(a1) << 16);
  *(unsigned*)(out + (size_t)node * 128 + fo) = o;
}

// ---------------- fused GEMM1+GEMM2, weights LDS-resident ----------------
__launch_bounds__(256, 3)
__global__ void k_gemm12(const float* __restrict__ F, int M,
                         const u16* __restrict__ W1t, const float* __restrict__ b1,
                         const u16* __restrict__ W2t, const float* __restrict__ b2,
                         u16* __restrict__ C) {
  __shared__ u16 Wsl[128][128];  // 32 KB, 8-group XOR swizzle
  __shared__ u16 Hsl[64][136];   // 17 KB: A-tile (bf16) then h1-tile
  int t = threadIdx.x;
  int wave = t >> 6, lane = t & 63;
  int quad = lane >> 4, l16 = lane & 15;
  int row0 = blockIdx.x * 64;
  int lg16 = lane & 15;

  // stage A: fp32 -> bf16 into Hsl. thread t: row t>>2, quarter t&3 (32 cols)
  {
    int r = t >> 2, q = t & 3;
    int grow = min(row0 + r, M - 1);
#pragma unroll
    for (int j = 0; j < 4; ++j) {
      float4 f0 = *(const float4*)(F + (size_t)grow * 128 + q * 32 + j * 8);
      float4 f1 = *(const float4*)(F + (size_t)grow * 128 + q * 32 + j * 8 + 4);
      u16x8 av;
      av[0] = f2b(f0.x); av[1] = f2b(f0.y); av[2] = f2b(f0.z); av[3] = f2b(f0.w);
      av[4] = f2b(f1.x); av[5] = f2b(f1.y); av[6] = f2b(f1.z); av[7] = f2b(f1.w);
      *(u16x8*)&Hsl[r][q * 32 + j * 8] = av;
    }
  }
  // stage W1t resident (swizzled)
#pragma unroll
  for (int i = 0; i < 8; ++i) {
    int rbase = wave * 32 + i * 4;
    int wrow = rbase + (lane >> 4);
    int grp = lg16 ^ (wrow & 7);
    glds16(W1t + (size_t)wrow * 128 + grp * 8, &Wsl[rbase][0]);
  }
  __syncthreads();

  f32x4 zero = {0.f, 0.f, 0.f, 0.f};
  f32x4 acc[4][2];
#pragma unroll
  for (int i = 0; i < 4; ++i) { acc[i][0] = zero; acc[i][1] = zero; }

  // phase 1: h1 = F @ W1 (barrier-free)
#pragma unroll
  for (int c = 0; c < 4; ++c) {
    v8bf a_frag[4], b_frag[2];
#pragma unroll
    for (int rt = 0; rt < 4; ++rt)
      a_frag[rt] = *(const v8bf*)&Hsl[rt * 16 + l16][c * 32 + quad * 8];
#pragma unroll
    for (int ct = 0; ct < 2; ++ct) {
      int col = wave * 32 + ct * 16 + l16;
      int g = (c * 4 + quad) ^ (col & 7);
      b_frag[ct] = *(const v8bf*)&Wsl[col][g * 8];
    }
#pragma unroll
    for (int rt = 0; rt < 4; ++rt)
#pragma unroll
      for (int ct = 0; ct < 2; ++ct)
        acc[rt][ct] = __builtin_amdgcn_mfma_f32_16x16x32_bf16(
            a_frag[rt], b_frag[ct], acc[rt][ct], 0, 0, 0);
  }
  __syncthreads();

  // write h1 = leaky(acc + b1) into Hsl; stage W2t over Wsl
  {
    float bb0 = b1[wave * 32 + l16], bb1 = b1[wave * 32 + 16 + l16];
#pragma unroll
    for (int rt = 0; rt < 4; ++rt)
#pragma unroll
      for (int ct = 0; ct < 2; ++ct) {
        int col = wave * 32 + ct * 16 + l16;
        float bb = ct ? bb1 : bb0;
#pragma unroll
        for (int r = 0; r < 4; ++r) {
          int row = rt * 16 + quad * 4 + r;
          float v = acc[rt][ct][r] + bb;
          v = v > 0.f ? v : 0.01f * v;
          Hsl[row][col] = f2b(v);
        }
      }
  }
#pragma unroll
  for (int i = 0; i < 8; ++i) {
    int rbase = wave * 32 + i * 4;
    int wrow = rbase + (lane >> 4);
    int grp = lg16 ^ (wrow & 7);
    glds16(W2t + (size_t)wrow * 128 + grp * 8, &Wsl[rbase][0]);
  }
  __syncthreads();

  f32x4 acc2[4][2];
#pragma unroll
  for (int i = 0; i < 4; ++i) { acc2[i][0] = zero; acc2[i][1] = zero; }

  // phase 2: T0 = h1 @ W2 (barrier-free)
#pragma unroll
  for (int c = 0; c < 4; ++c) {
    v8bf a_frag[4], b_frag[2];
#pragma unroll
    for (int rt = 0; rt < 4; ++rt)
      a_frag[rt] = *(const v8bf*)&Hsl[rt * 16 + l16][c * 32 + quad * 8];
#pragma unroll
    for (int ct = 0; ct < 2; ++ct) {
      int col = wave * 32 + ct * 16 + l16;
      int g = (c * 4 + quad) ^ (col & 7);
      b_frag[ct] = *(const v8bf*)&Wsl[col][g * 8];
    }
#pragma unroll
    for (int rt = 0; rt < 4; ++rt)
#pragma unroll
      for (int ct = 0; ct < 2; ++ct)
        acc2[rt][ct] = __builtin_amdgcn_mfma_f32_16x16x32_bf16(
            a_frag[rt], b_frag[ct], acc2[rt][ct], 0, 0, 0);
  }
  {
    float bb0 = b2[wave * 32 + l16], bb1 = b2[wave * 32 + 16 + l16];
#pragma unroll
    for (int rt = 0; rt < 4; ++rt)
#pragma unroll
      for (int ct = 0; ct < 2; ++ct) {
        int col = wave * 32 + ct * 16 + l16;
        float bb = ct ? bb1 : bb0;
#pragma unroll
        for (int r = 0; r < 4; ++r) {
          int row = row0 + rt * 16 + quad * 4 + r;
          if (row < M) {
            float v = acc2[rt][ct][r] + bb;
            v = v > 0.f ? v : 0.01f * v;
            C[(size_t)row * 128 + col] = f2b(v);
          }
        }
      }
  }
}

// ---------------- fused GEMM3+GEMM4 v3 (36 KB LDS, 4 blocks/CU) ----------------
// h3 = leaky( leaky([T0|T1|T2]@Wft + bf) @ W4t + b4 ). Phase 2 exchanges h2
// through a 16 KB half-K buffer in two rounds (acc2 persists across rounds).
__launch_bounds__(256, 4)
__global__ void k_gemm34(const u16* __restrict__ A0, const u16* __restrict__ A1,
                         const u16* __restrict__ A2, int M,
                         const u16* __restrict__ Wft, const float* __restrict__ bf,
                         const u16* __restrict__ W4t, const float* __restrict__ b4,
                         u16* __restrict__ C) {
  __shared__ u16 Asl[64][32];    // 4 KB
  __shared__ u16 Bsl[256][32];   // 16 KB
  __shared__ u16 h2sl[64][128];  // 16 KB (half-K exchange, XOR swizzle)
  int t = threadIdx.x;
  int wave = t >> 6, lane = t & 63;
  int quad = lane >> 4, l16 = lane & 15;
  int row0 = blockIdx.x * 64;
  int lrow = lane >> 2, lg = lane & 3;
  int sgg = lg ^ ((lrow >> 1) & 3);
  int rgs = quad ^ ((l16 >> 1) & 3);

  f32x4 zero = {0.f, 0.f, 0.f, 0.f};
  f32x4 acc[4][4];
#pragma unroll
  for (int i = 0; i < 4; ++i)
#pragma unroll
    for (int j = 0; j < 4; ++j) acc[i][j] = zero;

  // phase 1: h2[64,256] = [T0|T1|T2] @ Wft (wave owns cols wave*64..+64)
  for (int k0 = 0; k0 < 384; k0 += 32) {
    const u16* Ap = k0 < 128 ? A0 : (k0 < 256 ? A1 : A2);
    int kc = k0 & 127;
    {
      int grow = min(row0 + wave * 16 + lrow, M - 1);
      glds16(Ap + (size_t)grow * 128 + kc + sgg * 8, &Asl[wave * 16][0]);
    }
#pragma unroll
    for (int i = 0; i < 4; ++i)
      glds16(Wft + (size_t)(wave * 64 + i * 16 + lrow) * 384 + k0 + sgg * 8,
             &Bsl[wave * 64 + i * 16][0]);
    __syncthreads();
    v8bf a_frag[4], b_frag[4];
#pragma unroll
    for (int rt = 0; rt < 4; ++rt)
      a_frag[rt] = *(const v8bf*)&Asl[rt * 16 + l16][rgs * 8];
#pragma unroll
    for (int ct = 0; ct < 4; ++ct)
      b_frag[ct] = *(const v8bf*)&Bsl[wave * 64 + ct * 16 + l16][rgs * 8];
#pragma unroll
    for (int rt = 0; rt < 4; ++rt)
#pragma unroll
      for (int ct = 0; ct < 4; ++ct)
        acc[rt][ct] = __builtin_amdgcn_mfma_f32_16x16x32_bf16(
            a_frag[rt], b_frag[ct], acc[rt][ct], 0, 0, 0);
    __syncthreads();
  }

  f32x4 acc2[4][4];
#pragma unroll
  for (int i = 0; i < 4; ++i)
#pragma unroll
    for (int j = 0; j < 4; ++j) acc2[i][j] = zero;

  float bbf0 = bf[wave * 64 + l16], bbf1 = bf[wave * 64 + 16 + l16];
  float bbf2 = bf[wave * 64 + 32 + l16], bbf3 = bf[wave * 64 + 48 + l16];

  // phase 2, two half-K rounds: rnd r uses h2 cols [128r,128r+128) from waves 2r/2r+1
#pragma unroll
  for (int rnd = 0; rnd < 2; ++rnd) {
    if ((wave >> 1) == rnd) {
      int lcol0 = (wave & 1) * 64;  // local col base within the 128
      float bbs[4] = {bbf0, bbf1, bbf2, bbf3};
#pragma unroll
      for (int rt = 0; rt < 4; ++rt)
#pragma unroll
        for (int ct = 0; ct < 4; ++ct) {
          int c = lcol0 + ct * 16 + l16;  // 0..127
#pragma unroll
          for (int r = 0; r < 4; ++r) {
            int row = rt * 16 + quad * 4 + r;
            float v = acc[rt][ct][r] + bbs[ct];
            v = v > 0.f ? v : 0.01f * v;
            int gs = (c >> 3) ^ (row & 7);
            h2sl[row][gs * 8 + (c & 7)] = f2b(v);
          }
        }
    }
    __syncthreads();
    for (int k0 = 0; k0 < 128; k0 += 32) {
#pragma unroll
      for (int i = 0; i < 4; ++i)
        glds16(W4t + (size_t)(wave * 64 + i * 16 + lrow) * 256 + rnd * 128 + k0 + sgg * 8,
               &Bsl[wave * 64 + i * 16][0]);
      __syncthreads();
      v8bf a_frag[4], b_frag[4];
#pragma unroll
      for (int rt = 0; rt < 4; ++rt) {
        int r = rt * 16 + l16;
        int g = ((k0 >> 3) + quad) ^ (r & 7);
        a_frag[rt] = *(const v8bf*)&h2sl[r][g * 8];
      }
#pragma unroll
      for (int ct = 0; ct < 4; ++ct)
        b_frag[ct] = *(const v8bf*)&Bsl[wave * 64 + ct * 16 + l16][rgs * 8];
#pragma unroll
      for (int rt = 0; rt < 4; ++rt)
#pragma unroll
        for (int ct = 0; ct < 4; ++ct)
          acc2[rt][ct] = __builtin_amdgcn_mfma_f32_16x16x32_bf16(
              a_frag[rt], b_frag[ct], acc2[rt][ct], 0, 0, 0);
      __syncthreads();
    }
  }
  {
    float bb0 = b4[wave * 64 + l16], bb1 = b4[wave * 64 + 16 + l16];
    float bb2 = b4[wave * 64 + 32 + l16], bb3 = b4[wave * 64 + 48 + l16];
    float bbs[4] = {bb0, bb1, bb2, bb3};
#pragma unroll
    for (int rt = 0; rt < 4; ++rt)
#pragma unroll
      for (int ct = 0; ct < 4; ++ct) {
        int col = wave * 64 + ct * 16 + l16;
#pragma unroll
        for (int r = 0; r < 4; ++r) {
          int row = row0 + rt * 16 + quad * 4 + r;
          if (row < M) {
            float v = acc2[rt][ct][r] + bbs[ct];
            v = v > 0.f ? v : 0.01f * v;
            C[(size_t)row * 256 + col] = f2b(v);
          }
        }
      }
  }
}

// ---------------- fp32 tiled GEMM (graph-level, tiny) ----------------
__launch_bounds__(256)
__global__ void k_gemm(const float* __restrict__ A0, int M, int K,
                       const float* __restrict__ B, int Nc,
                       const float* __restrict__ bias, int act,
                       float* __restrict__ C) {
  __shared__ float As[16][68];
  __shared__ float Bs[16][68];
  int t = threadIdx.x;
  int tx = t & 15, ty = t >> 4;
  int row0 = blockIdx.y * 64, col0 = blockIdx.x * 64;
  int ar = t >> 2, ac4 = (t & 3) << 2;
  int br = t >> 4, bc4 = (t & 15) << 2;
  float acc[4][4] = {{0.f}};
  for (int k0 = 0; k0 < K; k0 += 16) {
    int arow = row0 + ar;
    float4 av = make_float4(0.f, 0.f, 0.f, 0.f);
    if (arow < M) av = *(const float4*)(A0 + (size_t)arow * K + k0 + ac4);
    As[ac4 + 0][ar] = av.x; As[ac4 + 1][ar] = av.y;
    As[ac4 + 2][ar] = av.z; As[ac4 + 3][ar] = av.w;
    float4 bv = *(const float4*)(B + (size_t)(k0 + br) * Nc + col0 + bc4);
    *(float4*)&Bs[br][bc4] = bv;
    __syncthreads();
#pragma unroll
    for (int kk = 0; kk < 16; ++kk) {
      float4 a4 = *(const float4*)&As[kk][ty << 2];
      float4 b4 = *(const float4*)&Bs[kk][tx << 2];
      float a[4] = {a4.x, a4.y, a4.z, a4.w};
      float b[4] = {b4.x, b4.y, b4.z, b4.w};
#pragma unroll
      for (int i = 0; i < 4; ++i)
#pragma unroll
        for (int j = 0; j < 4; ++j) acc[i][j] = fmaf(a[i], b[j], acc[i][j]);
    }
    __syncthreads();
  }
#pragma unroll
  for (int i = 0; i < 4; ++i) {
    int r = row0 + (ty << 2) + i;
    if (r < M) {
#pragma unroll
      for (int j = 0; j < 4; ++j) {
        int c = col0 + (tx << 2) + j;
        float v = acc[i][j];
        if (bias) v += bias[c];
        if (act) v = v > 0.f ? v : 0.01f * v;
        C[(size_t)r * Nc + c] = v;
      }
    }
  }
}

// two independent 128->256 graph GEMMs sharing A (S1 = act(xlx@W8+b8),
// S4 = act(xlx@W56+b56)); blockIdx.z selects the pair.
__launch_bounds__(256)
__global__ void k_gemm2w(const float* __restrict__ A0, int M,
                         const float* __restrict__ B0, const float* __restrict__ bias0,
                         float* __restrict__ C0,
                         const float* __restrict__ B1, const float* __restrict__ bias1,
                         float* __restrict__ C1) {
  const float* B = blockIdx.z ? B1 : B0;
  const float* bias = blockIdx.z ? bias1 : bias0;
  float* C = blockIdx.z ? C1 : C0;
  __shared__ float As[16][68];
  __shared__ float Bs[16][68];
  int t = threadIdx.x;
  int tx = t & 15, ty = t >> 4;
  int row0 = blockIdx.y * 64, col0 = blockIdx.x * 64;
  int ar = t >> 2, ac4 = (t & 3) << 2;
  int br = t >> 4, bc4 = (t & 15) << 2;
  float acc[4][4] = {{0.f}};
  for (int k0 = 0; k0 < 128; k0 += 16) {
    int arow = row0 + ar;
    float4 av = make_float4(0.f, 0.f, 0.f, 0.f);
    if (arow < M) av = *(const float4*)(A0 + (size_t)arow * 128 + k0 + ac4);
    As[ac4 + 0][ar] = av.x; As[ac4 + 1][ar] = av.y;
    As[ac4 + 2][ar] = av.z; As[ac4 + 3][ar] = av.w;
    float4 bv = *(const float4*)(B + (size_t)(k0 + br) * 256 + col0 + bc4);
    *(float4*)&Bs[br][bc4] = bv;
    __syncthreads();
#pragma unroll
    for (int kk = 0; kk < 16; ++kk) {
      float4 a4 = *(const float4*)&As[kk][ty << 2];
      float4 b4 = *(const float4*)&Bs[kk][tx << 2];
      float a[4] = {a4.x, a4.y, a4.z, a4.w};
      float b[4] = {b4.x, b4.y, b4.z, b4.w};
#pragma unroll
      for (int i = 0; i < 4; ++i)
#pragma unroll
        for (int j = 0; j < 4; ++j) acc[i][j] = fmaf(a[i], b[j], acc[i][j]);
    }
    __syncthreads();
  }
#pragma unroll
  for (int i = 0; i < 4; ++i) {
    int r = row0 + (ty << 2) + i;
    if (r < M) {
#pragma unroll
      for (int j = 0; j < 4; ++j) {
        int c = col0 + (tx << 2) + j;
        float v = acc[i][j] + bias[c];
        v = v > 0.f ? v : 0.01f * v;
        C[(size_t)r * 256 + c] = v;
      }
    }
  }
}

// ---------------- weight-prep mega-kernel (one dispatch) ----------------
__launch_bounds__(256)
__global__ void k_prep(const float* __restrict__ chebW, const float* __restrict__ W3,
                       u16* __restrict__ Wft, const float* __restrict__ chebB,
                       const float* __restrict__ b3, float* __restrict__ bf,
                       const float* __restrict__ W1, u16* __restrict__ W1t,
                       const float* __restrict__ W2, u16* __restrict__ W2t,
                       const float* __restrict__ W4, u16* __restrict__ W4t,
                       const float* __restrict__ W5, const float* __restrict__ W6,
                       const float* __restrict__ b5, const float* __restrict__ b6,
                       float* __restrict__ W56, float* __restrict__ b56,
                       const int* __restrict__ deg, float* __restrict__ dis, int N) {
  int b = blockIdx.x, t = threadIdx.x;
  if (b < 384) {
    int kk = b, c2 = t;
    int k = kk >> 7, r = kk & 127;
    float acc = 0.f;
    for (int j = 0; j < 512; ++j) {
      int i = j >> 7, cj = j & 127;
      float a = chebW[((size_t)((i * 3 + k) * 128 + r)) * 128 + cj];
      acc = fmaf(a, W3[(size_t)j * 256 + c2], acc);
    }
    Wft[(size_t)c2 * 384 + kk] = f2b(acc);
  } else if (b == 384) {
    int c2 = t;
    float acc = b3[c2];
    for (int j = 0; j < 512; ++j) {
      int i = j >> 7, cj = j & 127;
      acc = fmaf(chebB[i * 128 + cj], W3[(size_t)j * 256 + c2], acc);
    }
    bf[c2] = acc;
  } else if (b < 769) {
    int idx = (b - 385) * 256 + t;
    if (idx < 16384) {
      int n = idx >> 7, k = idx & 127;
      W1t[idx] = f2b(W1[(size_t)k * 128 + n]);
    } else if (idx < 32768) {
      int j = idx - 16384; int n = j >> 7, k = j & 127;
      W2t[j] = f2b(W2[(size_t)k * 128 + n]);
    } else {
      int j = idx - 32768; int n = j >> 8, k = j & 255;
      W4t[j] = f2b(W4[(size_t)k * 256 + n]);
    }
  } else if (b < 897) {
    int j = (b - 769) * 256 + t;
    int r = j >> 8, c = j & 255;
    float acc = 0.f;
    for (int k = 0; k < 256; ++k)
      acc = fmaf(W5[(size_t)r * 256 + k], W6[(size_t)k * 256 + c], acc);
    W56[j] = acc;
  } else if (b == 897) {
    int c = t;
    float acc = b6[c];
    for (int k = 0; k < 256; ++k)
      acc = fmaf(b5[k], W6[(size_t)k * 256 + c], acc);
    b56[c] = acc;
  } else {
    int base = (b - 898) * 1024 + t * 4;
    if (base + 3 < N) {
      int4 dv = *(const int4*)(deg + base);
      float4 dd;
      dd.x = dv.x > 0 ? rsqrtf((float)dv.x) : 0.f;
      dd.y = dv.y > 0 ? rsqrtf((float)dv.y) : 0.f;
      dd.z = dv.z > 0 ? rsqrtf((float)dv.z) : 0.f;
      dd.w = dv.w > 0 ? rsqrtf((float)dv.w) : 0.f;
      *(float4*)(dis + base) = dd;
    } else {
      for (int i = base; i < N; ++i) {
        int d = deg[i]; dis[i] = d > 0 ? rsqrtf((float)d) : 0.f;
      }
    }
  }
}

// ---------------- pooling / epilogue ----------------
__launch_bounds__(256)
__global__ void k_pool(const u16* __restrict__ h3, const float* __restrict__ tmp2,
                       const float* __restrict__ xlx2, float pw,
                       float* __restrict__ hc, int npg) {
  int g = blockIdx.x;
  int t = threadIdx.x;
  int lane = t & 63, w = t >> 6;
  const float* tp = tmp2 + (size_t)g * 256;
  float t0 = tp[lane], t1 = tp[64 + lane], t2 = tp[128 + lane], t3 = tp[192 + lane];
  float a0 = 0.f, a1 = 0.f, a2 = 0.f, a3 = 0.f;
  for (int idx = w; idx < npg; idx += 4) {
    const u16* hp = h3 + ((size_t)g * npg + idx) * 256;
    float v0 = b2f(hp[lane]), v1 = b2f(hp[64 + lane]);
    float v2 = b2f(hp[128 + lane]), v3 = b2f(hp[192 + lane]);
    float p = v0 * t0 + v1 * t1 + v2 * t2 + v3 * t3;
#pragma unroll
    for (int o = 1; o < 64; o <<= 1) p += __shfl_xor(p, o, 64);
    a0 = fmaf(p, v0, a0); a1 = fmaf(p, v1, a1);
    a2 = fmaf(p, v2, a2); a3 = fmaf(p, v3, a3);
  }
  __shared__ float red[4][256];
  red[w][lane] = a0; red[w][64 + lane] = a1;
  red[w][128 + lane] = a2; red[w][192 + lane] = a3;
  __syncthreads();
  float s = red[0][t] + red[1][t] + red[2][t] + red[3][t];
  hc[(size_t)g * 512 + t] = s * pw;
  hc[(size_t)g * 512 + 256 + t] = xlx2[(size_t)g * 256 + t];
}

__launch_bounds__(256)
__global__ void k_bnstats(const float* __restrict__ hc, float* __restrict__ mu,
                          float* __restrict__ rstd, int G) {
  int c = blockIdx.x;  // 512
  int t = threadIdx.x;
  float s = 0.f, s2 = 0.f;
  for (int g = t; g < G; g += 256) {
    float v = hc[(size_t)g * 512 + c];
    s += v; s2 = fmaf(v, v, s2);
  }
#pragma unroll
  for (int o = 1; o < 64; o <<= 1) { s += __shfl_xor(s, o, 64); s2 += __shfl_xor(s2, o, 64); }
  __shared__ float rs[4], rs2[4];
  int w = t >> 6, lane = t & 63;
  if (lane == 0) { rs[w] = s; rs2[w] = s2; }
  __syncthreads();
  if (t == 0) {
    float S = rs[0] + rs[1] + rs[2] + rs[3];
    float S2 = rs2[0] + rs2[1] + rs2[2] + rs2[3];
    float m = S / (float)G;
    float v = fmaxf(S2 / (float)G - m * m, 0.f);
    mu[c] = m;
    rstd[c] = rsqrtf(v + 1e-5f);
  }
}

__launch_bounds__(256)
__global__ void k_final(const float* __restrict__ hc, const float* __restrict__ mu,
                        const float* __restrict__ rstd, const float* __restrict__ gamma,
                        const float* __restrict__ beta, const float* __restrict__ W7,
                        const float* __restrict__ b7, float* __restrict__ out) {
  int g = blockIdx.x, t = threadIdx.x;
  int lane = t & 63, w = t >> 6;
  float p0 = 0.f, p1 = 0.f;
  for (int c = t; c < 512; c += 256) {
    float xn = fmaf(gamma[c] * (hc[(size_t)g * 512 + c] - mu[c]), rstd[c], beta[c]);
    p0 = fmaf(xn, W7[c * 2 + 0], p0);
    p1 = fmaf(xn, W7[c * 2 + 1], p1);
  }
#pragma unroll
  for (int o = 1; o < 64; o <<= 1) { p0 += __shfl_xor(p0, o, 64); p1 += __shfl_xor(p1, o, 64); }
  __shared__ float r0[4], r1[4];
  if (lane == 0) { r0[w] = p0; r1[w] = p1; }
  __syncthreads();
  if (t == 0) out[(size_t)g * 2 + 0] = r0[0] + r0[1] + r0[2] + r0[3] + b7[0];
  if (t == 1) out[(size_t)g * 2 + 1] = r1[0] + r1[1] + r1[2] + r1[3] + b7[1];
}

// ---------------------------------------------------------------------------

extern "C" void kernel_launch(void* const* d_in, const int* in_sizes, int n_in,
                              void* d_out, int out_size, void* d_ws, size_t ws_size,
                              hipStream_t stream) {
  const float* features = (const float*)d_in[0];
  const int* eidx = (const int*)d_in[1];
  const float* xlx = (const float*)d_in[3];
  const float* W1 = (const float*)d_in[4];  const float* b1 = (const float*)d_in[5];
  const float* W2 = (const float*)d_in[6];  const float* b2 = (const float*)d_in[7];
  const float* chebW = (const float*)d_in[8]; const float* chebB = (const float*)d_in[9];
  const float* W3 = (const float*)d_in[10]; const float* b3 = (const float*)d_in[11];
  const float* W4 = (const float*)d_in[12]; const float* b4 = (const float*)d_in[13];
  const float* W5 = (const float*)d_in[14]; const float* b5 = (const float*)d_in[15];
  const float* W6 = (const float*)d_in[16]; const float* b6 = (const float*)d_in[17];
  const float* W8 = (const float*)d_in[18]; const float* b8 = (const float*)d_in[19];
  const float* W9 = (const float*)d_in[20]; const float* b9 = (const float*)d_in[21];
  const float* W7 = (const float*)d_in[22]; const float* b7 = (const float*)d_in[23];
  const float* gamma = (const float*)d_in[24]; const float* beta = (const float*)d_in[25];

  const int N = in_sizes[0] / 128;  // 100000
  const int E = in_sizes[1] / 2;    // 600000
  const int G = in_sizes[3] / 128;  // 1000
  const int npg = N / G;            // 100

  const int* src = eidx;
  const int* dst = eidx + E;

  // ---- workspace layout ----
  uint8_t* base = (uint8_t*)d_ws;
  size_t off = 0;
  auto alloc = [&](size_t bytes) {
    uint8_t* p = base + off;
    off += (bytes + 255) & ~(size_t)255;
    return p;
  };
  size_t nbh = (size_t)N * 128;
  u16* T0b = (u16*)alloc(nbh * 2);
  u16* T1b = (u16*)alloc(nbh * 2);
  u16* T2b = (u16*)alloc(nbh * 2);
  u16* h3b = (u16*)alloc((size_t)N * 256 * 2);
  float* bf = (float*)alloc(256 * 4);
  u16* W1t = (u16*)alloc(128 * 128 * 2);
  u16* W2t = (u16*)alloc(128 * 128 * 2);
  u16* Wft = (u16*)alloc(256 * 384 * 2);
  u16* W4t = (u16*)alloc(256 * 256 * 2);
  float* W56 = (float*)alloc(128 * 256 * 4);
  float* b56 = (float*)alloc(256 * 4);
  float* dis = (float*)alloc((size_t)N * 4);
  float* S1 = (float*)alloc((size_t)G * 256 * 4);
  float* S2 = (float*)alloc((size_t)G * 256 * 4);
  float* S4 = (float*)alloc((size_t)G * 256 * 4);
  float* hc = (float*)alloc((size_t)G * 512 * 4);
  float* mu = (float*)alloc(512 * 4);
  float* rstd = (float*)alloc(512 * 4);
  size_t zoff = off;
  int* deg = (int*)alloc((size_t)N * 4);
  int* indeg = (int*)alloc((size_t)N * 4);
  size_t zlen = off - zoff;
  int* rowptr = (int*)alloc(((size_t)N + 1) * 4);
  int* rowcur = (int*)alloc((size_t)N * 4);
  int* csre = (int*)alloc((size_t)E * 4);
  int* bsum = (int*)alloc(260 * 4);
  int* boff = (int*)alloc(260 * 4);
  if (off > ws_size)
    fprintf(stderr, "WARNING: ws too small: need %zu have %zu\n", off, ws_size);

  hipMemsetAsync(base + zoff, 0, zlen, stream);

  // CSR build
  k_hist<<<(E + 255) / 256, 256, 0, stream>>>(dst, indeg, E);
  int B = (N + 1023) / 1024;  // 98; must be <= 256
  k_scan1<<<B, 256, 0, stream>>>(indeg, rowptr, bsum, N);
  k_scan2<<<1, 256, 0, stream>>>(bsum, boff, B);
  k_scan3<<<B, 256, 0, stream>>>(rowptr, boff, rowcur, N, B);
  k_scatter<<<(E + 255) / 256, 256, 0, stream>>>(src, dst, rowcur, deg, csre, E);

  // weight prep + dis (after scatter's deg histogram)
  k_prep<<<898 + B, 256, 0, stream>>>(chebW, W3, Wft, chebB, b3, bf,
                                      W1, W1t, W2, W2t, W4, W4t,
                                      W5, W6, b5, b6, W56, b56, deg, dis, N);

  // node MLP fused: T0 = act(act(F@W1+b1)@W2+b2)
  k_gemm12<<<(N + 63) / 64, 256, 0, stream>>>(features, N, W1t, b1, W2t, b2, T0b);

  // propagation via CSR gather (no atomics)
  int ggrid = (N + 3) / 4;
  k_gather<<<ggrid, 256, 0, stream>>>(T0b, rowptr, csre, dis, nullptr, 1.0f, T1b, N);
  k_gather<<<ggrid, 256, 0, stream>>>(T1b, rowptr, csre, dis, T0b, 2.0f, T2b, N);

  // fused: h3 = act(act([T0|T1|T2]@Wft + bf) @ W4 + b4)
  k_gemm34<<<(N + 63) / 64, 256, 0, stream>>>(T0b, T1b, T2b, N, Wft, bf,
                                              W4t, b4, h3b);

  // graph-level chains (G=1000, fp32, cheap); W5/W6 folded into W56
  {
    dim3 grid2(256 / 64, (G + 63) / 64, 2);
    k_gemm2w<<<grid2, 256, 0, stream>>>(xlx, G, W8, b8, S1, W56, b56, S4);
    dim3 grid(256 / 64, (G + 63) / 64);
    k_gemm<<<grid, 256, 0, stream>>>(S1, G, 256, W9, 256, b9, 1, S2);
  }

  k_pool<<<G, 256, 0, stream>>>(h3b, S2, S4, 1.0f / (float)npg, hc, npg);
  k_bnstats<<<512, 256, 0, stream>>>(hc, mu, rstd, G);
  k_final<<<G, 256, 0, stream>>>(hc, mu, rstd, gamma, beta, W7, b7, (float*)d_out);
}

// Round 11
// 477.253 us; speedup vs baseline: 1.1725x; 1.1725x over previous
//
#include <hip/hip_runtime.h>
#include <cstdio>
#include <cstdint>

// ---------------------------------------------------------------------------
// GADGNN forward. R11: revert gemm34 to R9 v2 (R10's 4-blk/CU launch bound
// caused register spills: acc+acc2 live simultaneously > 128 VGPR budget);
// gather v3: quarter-wave edge split (16 lanes x 16B per row, unroll-2) ->
// serial miss-chain depth ~1 for avg degree 6.
//  - k_gemm12: GEMM1+GEMM2 fused, weights LDS-resident (barrier-free K-loop)
//  - prop() twice; Wcat@W3 and W5@W6 folded; dst-CSR gather (no fp32 atomics)
// ---------------------------------------------------------------------------

typedef unsigned short u16;
typedef __bf16 v8bf __attribute__((ext_vector_type(8)));
typedef float f32x4 __attribute__((ext_vector_type(4)));
typedef u16 u16x8 __attribute__((ext_vector_type(8)));

__device__ inline float b2f(u16 u) {
  union { unsigned int i; float f; } x; x.i = ((unsigned int)u) << 16; return x.f;
}
__device__ inline u16 f2b(float f) {  // RNE
  unsigned int u = __float_as_uint(f);
  unsigned int r = (u + 0x7fffu + ((u >> 16) & 1u)) >> 16;
  return (u16)r;
}

// async global->LDS, 16 B per lane; lds dest = base + lane*16 (wave-uniform base)
__device__ __forceinline__ void glds16(const u16* g, u16* l) {
  __builtin_amdgcn_global_load_lds(
      (const __attribute__((address_space(1))) void*)g,
      (__attribute__((address_space(3))) void*)l, 16, 0, 0);
}

// ---------------- prep kernels ----------------

__global__ void k_hist(const int* __restrict__ dst, int* __restrict__ indeg, int E) {
  int e = blockIdx.x * blockDim.x + threadIdx.x;
  if (e < E) atomicAdd(&indeg[dst[e]], 1);
}

__launch_bounds__(256)
__global__ void k_scan1(const int* __restrict__ indeg, int* __restrict__ rowptr,
                        int* __restrict__ bsum, int N) {
  int b = blockIdx.x, t = threadIdx.x;
  int base = b * 1024 + t * 4;
  int4 v = make_int4(0, 0, 0, 0);
  if (base + 3 < N) v = *(const int4*)(indeg + base);
  else if (base < N) {
    v.x = indeg[base];
    v.y = base + 1 < N ? indeg[base + 1] : 0;
    v.z = base + 2 < N ? indeg[base + 2] : 0;
  }
  int s = v.x + v.y + v.z + v.w;
  int lane = t & 63, w = t >> 6;
  int inc = s;
#pragma unroll
  for (int o = 1; o < 64; o <<= 1) { int u = __shfl_up(inc, o, 64); if (lane >= o) inc += u; }
  __shared__ int wsum[4];
  if (lane == 63) wsum[w] = inc;
  __syncthreads();
  int woff = 0;
#pragma unroll
  for (int i = 0; i < 4; ++i) if (i < w) woff += wsum[i];
  int excl = woff + inc - s;
  int4 o4;
  o4.x = excl; o4.y = o4.x + v.x; o4.z = o4.y + v.y; o4.w = o4.z + v.z;
  if (base + 3 < N) *(int4*)(rowptr + base) = o4;
  else if (base < N) {
    rowptr[base] = o4.x;
    if (base + 1 < N) rowptr[base + 1] = o4.y;
    if (base + 2 < N) rowptr[base + 2] = o4.z;
  }
  if (t == 255) bsum[b] = woff + inc;
}

__launch_bounds__(256)
__global__ void k_scan2(const int* __restrict__ bsum, int* __restrict__ boff, int B) {
  int t = threadIdx.x;
  int v = t < B ? bsum[t] : 0;
  int lane = t & 63, w = t >> 6;
  int inc = v;
#pragma unroll
  for (int o = 1; o < 64; o <<= 1) { int u = __shfl_up(inc, o, 64); if (lane >= o) inc += u; }
  __shared__ int wsum[4];
  if (lane == 63) wsum[w] = inc;
  __syncthreads();
  int woff = 0;
#pragma unroll
  for (int i = 0; i < 4; ++i) if (i < w) woff += wsum[i];
  if (t < B) boff[t] = woff + inc - v;
  if (t == 255) boff[B] = woff + inc;
}

__launch_bounds__(256)
__global__ void k_scan3(int* __restrict__ rowptr, const int* __restrict__ boff,
                        int* __restrict__ rowcur, int N, int B) {
  int b = blockIdx.x, t = threadIdx.x;
  int base = b * 1024 + t * 4;
  int add = boff[b];
  if (base + 3 < N) {
    int4 v = *(const int4*)(rowptr + base);
    v.x += add; v.y += add; v.z += add; v.w += add;
    *(int4*)(rowptr + base) = v;
    *(int4*)(rowcur + base) = v;
  } else if (base < N) {
    for (int i = base; i < N; ++i) { int v = rowptr[i] + add; rowptr[i] = v; rowcur[i] = v; }
  }
  if (b == 0 && t == 0) rowptr[N] = boff[B];
}

// scatter edges into CSR slots + out-degree histogram
__global__ void k_scatter(const int* __restrict__ src, const int* __restrict__ dst,
                          int* __restrict__ rowcur, int* __restrict__ deg,
                          int* __restrict__ csre, int E) {
  int e = blockIdx.x * blockDim.x + threadIdx.x;
  if (e >= E) return;
  int s = src[e];
  atomicAdd(&deg[s], 1);
  int p = atomicAdd(&rowcur[dst[e]], 1);
  csre[p] = s;
}

// out[d,:] = (-scale*dis[d]) * sum_e dis[s_e]*x[s_e,:]  (- sub[d,:] if sub)
// One wave per node, edges split across 4 quarter-waves (16 lanes x 16B = one
// full 256B row per quarter). Unroll-2 per quarter -> up to 8 rows in flight,
// serial chain depth ~1 for avg degree 6. Combine via 2 shfl_xor rounds.
__launch_bounds__(256)
__global__ void k_gather(const u16* __restrict__ x, const int* __restrict__ rowptr,
                         const int* __restrict__ csre, const float* __restrict__ dis,
                         const u16* __restrict__ sub, float scale,
                         u16* __restrict__ out, int N) {
  int node = blockIdx.x * 4 + (threadIdx.x >> 6);
  if (node >= N) return;
  int lane = threadIdx.x & 63;
  int q = lane >> 4, ql = lane & 15;
  int fo = ql * 8;  // 8 bf16 per lane
  int b = rowptr[node], e = rowptr[node + 1];
  float a[8] = {0.f, 0.f, 0.f, 0.f, 0.f, 0.f, 0.f, 0.f};
  int i = b + q;
  for (; i + 4 < e; i += 8) {  // pair: edges i and i+4 (independent loads)
    int s0 = csre[i], s1 = csre[i + 4];
    u16x8 v0 = *(const u16x8*)(x + (size_t)s0 * 128 + fo);
    u16x8 v1 = *(const u16x8*)(x + (size_t)s1 * 128 + fo);
    float w0 = dis[s0], w1 = dis[s1];
#pragma unroll
    for (int j = 0; j < 8; ++j) {
      a[j] = fmaf(w0, b2f(v0[j]), a[j]);
      a[j] = fmaf(w1, b2f(v1[j]), a[j]);
    }
  }
  if (i < e) {
    int s = csre[i];
    u16x8 v = *(const u16x8*)(x + (size_t)s * 128 + fo);
    float w = dis[s];
#pragma unroll
    for (int j = 0; j < 8; ++j) a[j] = fmaf(w, b2f(v[j]), a[j]);
  }
#pragma unroll
  for (int o = 16; o < 64; o <<= 1)
#pragma unroll
    for (int j = 0; j < 8; ++j) a[j] += __shfl_xor(a[j], o, 64);
  if (q == 0) {
    float m = -scale * dis[node];
    u16x8 o8;
    if (sub) {
      u16x8 sv = *(const u16x8*)(sub + (size_t)node * 128 + fo);
#pragma unroll
      for (int j = 0; j < 8; ++j) o8[j] = f2b(a[j] * m - b2f(sv[j]));
    } else {
#pragma unroll
      for (int j = 0; j < 8; ++j) o8[j] = f2b(a[j] * m);
    }
    *(u16x8*)(out + (size_t)node * 128 + fo) = o8;
  }
}

// ---------------- fused GEMM1+GEMM2, weights LDS-resident ----------------
__launch_bounds__(256, 3)
__global__ void k_gemm12(const float* __restrict__ F, int M,
                         const u16* __restrict__ W1t, const float* __restrict__ b1,
                         const u16* __restrict__ W2t, const float* __restrict__ b2,
                         u16* __restrict__ C) {
  __shared__ u16 Wsl[128][128];  // 32 KB, 8-group XOR swizzle
  __shared__ u16 Hsl[64][136];   // 17 KB: A-tile (bf16) then h1-tile
  int t = threadIdx.x;
  int wave = t >> 6, lane = t & 63;
  int quad = lane >> 4, l16 = lane & 15;
  int row0 = blockIdx.x * 64;
  int lg16 = lane & 15;

  // stage A: fp32 -> bf16 into Hsl. thread t: row t>>2, quarter t&3 (32 cols)
  {
    int r = t >> 2, q = t & 3;
    int grow = min(row0 + r, M - 1);
#pragma unroll
    for (int j = 0; j < 4; ++j) {
      float4 f0 = *(const float4*)(F + (size_t)grow * 128 + q * 32 + j * 8);
      float4 f1 = *(const float4*)(F + (size_t)grow * 128 + q * 32 + j * 8 + 4);
      u16x8 av;
      av[0] = f2b(f0.x); av[1] = f2b(f0.y); av[2] = f2b(f0.z); av[3] = f2b(f0.w);
      av[4] = f2b(f1.x); av[5] = f2b(f1.y); av[6] = f2b(f1.z); av[7] = f2b(f1.w);
      *(u16x8*)&Hsl[r][q * 32 + j * 8] = av;
    }
  }
  // stage W1t resident (swizzled)
#pragma unroll
  for (int i = 0; i < 8; ++i) {
    int rbase = wave * 32 + i * 4;
    int wrow = rbase + (lane >> 4);
    int grp = lg16 ^ (wrow & 7);
    glds16(W1t + (size_t)wrow * 128 + grp * 8, &Wsl[rbase][0]);
  }
  __syncthreads();

  f32x4 zero = {0.f, 0.f, 0.f, 0.f};
  f32x4 acc[4][2];
#pragma unroll
  for (int i = 0; i < 4; ++i) { acc[i][0] = zero; acc[i][1] = zero; }

  // phase 1: h1 = F @ W1 (barrier-free)
#pragma unroll
  for (int c = 0; c < 4; ++c) {
    v8bf a_frag[4], b_frag[2];
#pragma unroll
    for (int rt = 0; rt < 4; ++rt)
      a_frag[rt] = *(const v8bf*)&Hsl[rt * 16 + l16][c * 32 + quad * 8];
#pragma unroll
    for (int ct = 0; ct < 2; ++ct) {
      int col = wave * 32 + ct * 16 + l16;
      int g = (c * 4 + quad) ^ (col & 7);
      b_frag[ct] = *(const v8bf*)&Wsl[col][g * 8];
    }
#pragma unroll
    for (int rt = 0; rt < 4; ++rt)
#pragma unroll
      for (int ct = 0; ct < 2; ++ct)
        acc[rt][ct] = __builtin_amdgcn_mfma_f32_16x16x32_bf16(
            a_frag[rt], b_frag[ct], acc[rt][ct], 0, 0, 0);
  }
  __syncthreads();

  // write h1 = leaky(acc + b1) into Hsl; stage W2t over Wsl
  {
    float bb0 = b1[wave * 32 + l16], bb1 = b1[wave * 32 + 16 + l16];
#pragma unroll
    for (int rt = 0; rt < 4; ++rt)
#pragma unroll
      for (int ct = 0; ct < 2; ++ct) {
        int col = wave * 32 + ct * 16 + l16;
        float bb = ct ? bb1 : bb0;
#pragma unroll
        for (int r = 0; r < 4; ++r) {
          int row = rt * 16 + quad * 4 + r;
          float v = acc[rt][ct][r] + bb;
          v = v > 0.f ? v : 0.01f * v;
          Hsl[row][col] = f2b(v);
        }
      }
  }
#pragma unroll
  for (int i = 0; i < 8; ++i) {
    int rbase = wave * 32 + i * 4;
    int wrow = rbase + (lane >> 4);
    int grp = lg16 ^ (wrow & 7);
    glds16(W2t + (size_t)wrow * 128 + grp * 8, &Wsl[rbase][0]);
  }
  __syncthreads();

  f32x4 acc2[4][2];
#pragma unroll
  for (int i = 0; i < 4; ++i) { acc2[i][0] = zero; acc2[i][1] = zero; }

  // phase 2: T0 = h1 @ W2 (barrier-free)
#pragma unroll
  for (int c = 0; c < 4; ++c) {
    v8bf a_frag[4], b_frag[2];
#pragma unroll
    for (int rt = 0; rt < 4; ++rt)
      a_frag[rt] = *(const v8bf*)&Hsl[rt * 16 + l16][c * 32 + quad * 8];
#pragma unroll
    for (int ct = 0; ct < 2; ++ct) {
      int col = wave * 32 + ct * 16 + l16;
      int g = (c * 4 + quad) ^ (col & 7);
      b_frag[ct] = *(const v8bf*)&Wsl[col][g * 8];
    }
#pragma unroll
    for (int rt = 0; rt < 4; ++rt)
#pragma unroll
      for (int ct = 0; ct < 2; ++ct)
        acc2[rt][ct] = __builtin_amdgcn_mfma_f32_16x16x32_bf16(
            a_frag[rt], b_frag[ct], acc2[rt][ct], 0, 0, 0);
  }
  {
    float bb0 = b2[wave * 32 + l16], bb1 = b2[wave * 32 + 16 + l16];
#pragma unroll
    for (int rt = 0; rt < 4; ++rt)
#pragma unroll
      for (int ct = 0; ct < 2; ++ct) {
        int col = wave * 32 + ct * 16 + l16;
        float bb = ct ? bb1 : bb0;
#pragma unroll
        for (int r = 0; r < 4; ++r) {
          int row = row0 + rt * 16 + quad * 4 + r;
          if (row < M) {
            float v = acc2[rt][ct][r] + bb;
            v = v > 0.f ? v : 0.01f * v;
            C[(size_t)row * 128 + col] = f2b(v);
          }
        }
      }
  }
}

// ---------------- fused GEMM3+GEMM4 v2 (R9; 53 KB LDS, 3 blocks/CU) ----------
// h3 = leaky( leaky([T0|T1|T2]@Wft + bf) @ W4t + b4 ); h2 kept in LDS.
// NOTE: do NOT raise to 4 blocks/CU — acc+acc2 liveness would exceed the
// 128-VGPR budget and spill (R10 regression: FETCH/WRITE tripled).
__launch_bounds__(256, 3)
__global__ void k_gemm34(const u16* __restrict__ A0, const u16* __restrict__ A1,
                         const u16* __restrict__ A2, int M,
                         const u16* __restrict__ Wft, const float* __restrict__ bf,
                         const u16* __restrict__ W4t, const float* __restrict__ b4,
                         u16* __restrict__ C) {
  __shared__ u16 Asl[64][32];    // 4 KB
  __shared__ u16 Bsl[256][32];   // 16 KB
  __shared__ u16 h2sl[64][256];  // 32 KB (8-group XOR swizzle)
  int t = threadIdx.x;
  int wave = t >> 6, lane = t & 63;
  int quad = lane >> 4, l16 = lane & 15;
  int row0 = blockIdx.x * 64;
  int lrow = lane >> 2, lg = lane & 3;
  int sgg = lg ^ ((lrow >> 1) & 3);
  int rgs = quad ^ ((l16 >> 1) & 3);

  f32x4 zero = {0.f, 0.f, 0.f, 0.f};
  f32x4 acc[4][4];
#pragma unroll
  for (int i = 0; i < 4; ++i)
#pragma unroll
    for (int j = 0; j < 4; ++j) acc[i][j] = zero;

  // phase 1: h2[64,256] = [T0|T1|T2] @ Wft
  for (int k0 = 0; k0 < 384; k0 += 32) {
    const u16* Ap = k0 < 128 ? A0 : (k0 < 256 ? A1 : A2);
    int kc = k0 & 127;
    {
      int grow = min(row0 + wave * 16 + lrow, M - 1);
      glds16(Ap + (size_t)grow * 128 + kc + sgg * 8, &Asl[wave * 16][0]);
    }
#pragma unroll
    for (int i = 0; i < 4; ++i)
      glds16(Wft + (size_t)(wave * 64 + i * 16 + lrow) * 384 + k0 + sgg * 8,
             &Bsl[wave * 64 + i * 16][0]);
    __syncthreads();
    v8bf a_frag[4], b_frag[4];
#pragma unroll
    for (int rt = 0; rt < 4; ++rt)
      a_frag[rt] = *(const v8bf*)&Asl[rt * 16 + l16][rgs * 8];
#pragma unroll
    for (int ct = 0; ct < 4; ++ct)
      b_frag[ct] = *(const v8bf*)&Bsl[wave * 64 + ct * 16 + l16][rgs * 8];
#pragma unroll
    for (int rt = 0; rt < 4; ++rt)
#pragma unroll
      for (int ct = 0; ct < 4; ++ct)
        acc[rt][ct] = __builtin_amdgcn_mfma_f32_16x16x32_bf16(
            a_frag[rt], b_frag[ct], acc[rt][ct], 0, 0, 0);
    __syncthreads();
  }

  // write leaky(h2 + bf) into h2sl (swizzled)
  {
    float bb0 = bf[wave * 64 + l16], bb1 = bf[wave * 64 + 16 + l16];
    float bb2 = bf[wave * 64 + 32 + l16], bb3 = bf[wave * 64 + 48 + l16];
    float bbs[4] = {bb0, bb1, bb2, bb3};
#pragma unroll
    for (int rt = 0; rt < 4; ++rt)
#pragma unroll
      for (int ct = 0; ct < 4; ++ct) {
        int col = wave * 64 + ct * 16 + l16;
#pragma unroll
        for (int r = 0; r < 4; ++r) {
          int row = rt * 16 + quad * 4 + r;
          float v = acc[rt][ct][r] + bbs[ct];
          v = v > 0.f ? v : 0.01f * v;
          int gs = (col >> 3) ^ (row & 7);
          h2sl[row][gs * 8 + (col & 7)] = f2b(v);
        }
      }
  }
  __syncthreads();

  f32x4 acc2[4][4];
#pragma unroll
  for (int i = 0; i < 4; ++i)
#pragma unroll
    for (int j = 0; j < 4; ++j) acc2[i][j] = zero;

  // phase 2: h3 = leaky(h2) @ W4
  for (int k0 = 0; k0 < 256; k0 += 32) {
#pragma unroll
    for (int i = 0; i < 4; ++i)
      glds16(W4t + (size_t)(wave * 64 + i * 16 + lrow) * 256 + k0 + sgg * 8,
             &Bsl[wave * 64 + i * 16][0]);
    __syncthreads();
    v8bf a_frag[4], b_frag[4];
#pragma unroll
    for (int rt = 0; rt < 4; ++rt) {
      int r = rt * 16 + l16;
      int g = ((k0 >> 3) + quad) ^ (r & 7);
      a_frag[rt] = *(const v8bf*)&h2sl[r][g * 8];
    }
#pragma unroll
    for (int ct = 0; ct < 4; ++ct)
      b_frag[ct] = *(const v8bf*)&Bsl[wave * 64 + ct * 16 + l16][rgs * 8];
#pragma unroll
    for (int rt = 0; rt < 4; ++rt)
#pragma unroll
      for (int ct = 0; ct < 4; ++ct)
        acc2[rt][ct] = __builtin_amdgcn_mfma_f32_16x16x32_bf16(
            a_frag[rt], b_frag[ct], acc2[rt][ct], 0, 0, 0);
    __syncthreads();
  }
  {
    float bb0 = b4[wave * 64 + l16], bb1 = b4[wave * 64 + 16 + l16];
    float bb2 = b4[wave * 64 + 32 + l16], bb3 = b4[wave * 64 + 48 + l16];
    float bbs[4] = {bb0, bb1, bb2, bb3};
#pragma unroll
    for (int rt = 0; rt < 4; ++rt)
#pragma unroll
      for (int ct = 0; ct < 4; ++ct) {
        int col = wave * 64 + ct * 16 + l16;
#pragma unroll
        for (int r = 0; r < 4; ++r) {
          int row = row0 + rt * 16 + quad * 4 + r;
          if (row < M) {
            float v = acc2[rt][ct][r] + bbs[ct];
            v = v > 0.f ? v : 0.01f * v;
            C[(size_t)row * 256 + col] = f2b(v);
          }
        }
      }
  }
}

// ---------------- fp32 tiled GEMM (graph-level, tiny) ----------------
__launch_bounds__(256)
__global__ void k_gemm(const float* __restrict__ A0, int M, int K,
                       const float* __restrict__ B, int Nc,
                       const float* __restrict__ bias, int act,
                       float* __restrict__ C) {
  __shared__ float As[16][68];
  __shared__ float Bs[16][68];
  int t = threadIdx.x;
  int tx = t & 15, ty = t >> 4;
  int row0 = blockIdx.y * 64, col0 = blockIdx.x * 64;
  int ar = t >> 2, ac4 = (t & 3) << 2;
  int br = t >> 4, bc4 = (t & 15) << 2;
  float acc[4][4] = {{0.f}};
  for (int k0 = 0; k0 < K; k0 += 16) {
    int arow = row0 + ar;
    float4 av = make_float4(0.f, 0.f, 0.f, 0.f);
    if (arow < M) av = *(const float4*)(A0 + (size_t)arow * K + k0 + ac4);
    As[ac4 + 0][ar] = av.x; As[ac4 + 1][ar] = av.y;
    As[ac4 + 2][ar] = av.z; As[ac4 + 3][ar] = av.w;
    float4 bv = *(const float4*)(B + (size_t)(k0 + br) * Nc + col0 + bc4);
    *(float4*)&Bs[br][bc4] = bv;
    __syncthreads();
#pragma unroll
    for (int kk = 0; kk < 16; ++kk) {
      float4 a4 = *(const float4*)&As[kk][ty << 2];
      float4 b4 = *(const float4*)&Bs[kk][tx << 2];
      float a[4] = {a4.x, a4.y, a4.z, a4.w};
      float b[4] = {b4.x, b4.y, b4.z, b4.w};
#pragma unroll
      for (int i = 0; i < 4; ++i)
#pragma unroll
        for (int j = 0; j < 4; ++j) acc[i][j] = fmaf(a[i], b[j], acc[i][j]);
    }
    __syncthreads();
  }
#pragma unroll
  for (int i = 0; i < 4; ++i) {
    int r = row0 + (ty << 2) + i;
    if (r < M) {
#pragma unroll
      for (int j = 0; j < 4; ++j) {
        int c = col0 + (tx << 2) + j;
        float v = acc[i][j];
        if (bias) v += bias[c];
        if (act) v = v > 0.f ? v : 0.01f * v;
        C[(size_t)r * Nc + c] = v;
      }
    }
  }
}

// two independent 128->256 graph GEMMs sharing A; blockIdx.z selects weights.
__launch_bounds__(256)
__global__ void k_gemm2w(const float* __restrict__ A0, int M,
                         const float* __restrict__ B0, const float* __restrict__ bias0,
                         float* __restrict__ C0,
                         const float* __restrict__ B1, const float* __restrict__ bias1,
                         float* __restrict__ C1) {
  const float* B = blockIdx.z ? B1 : B0;
  const float* bias = blockIdx.z ? bias1 : bias0;
  float* C = blockIdx.z ? C1 : C0;
  __shared__ float As[16][68];
  __shared__ float Bs[16][68];
  int t = threadIdx.x;
  int tx = t & 15, ty = t >> 4;
  int row0 = blockIdx.y * 64, col0 = blockIdx.x * 64;
  int ar = t >> 2, ac4 = (t & 3) << 2;
  int br = t >> 4, bc4 = (t & 15) << 2;
  float acc[4][4] = {{0.f}};
  for (int k0 = 0; k0 < 128; k0 += 16) {
    int arow = row0 + ar;
    float4 av = make_float4(0.f, 0.f, 0.f, 0.f);
    if (arow < M) av = *(const float4*)(A0 + (size_t)arow * 128 + k0 + ac4);
    As[ac4 + 0][ar] = av.x; As[ac4 + 1][ar] = av.y;
    As[ac4 + 2][ar] = av.z; As[ac4 + 3][ar] = av.w;
    float4 bv = *(const float4*)(B + (size_t)(k0 + br) * 256 + col0 + bc4);
    *(float4*)&Bs[br][bc4] = bv;
    __syncthreads();
#pragma unroll
    for (int kk = 0; kk < 16; ++kk) {
      float4 a4 = *(const float4*)&As[kk][ty << 2];
      float4 b4 = *(const float4*)&Bs[kk][tx << 2];
      float a[4] = {a4.x, a4.y, a4.z, a4.w};
      float b[4] = {b4.x, b4.y, b4.z, b4.w};
#pragma unroll
      for (int i = 0; i < 4; ++i)
#pragma unroll
        for (int j = 0; j < 4; ++j) acc[i][j] = fmaf(a[i], b[j], acc[i][j]);
    }
    __syncthreads();
  }
#pragma unroll
  for (int i = 0; i < 4; ++i) {
    int r = row0 + (ty << 2) + i;
    if (r < M) {
#pragma unroll
      for (int j = 0; j < 4; ++j) {
        int c = col0 + (tx << 2) + j;
        float v = acc[i][j] + bias[c];
        v = v > 0.f ? v : 0.01f * v;
        C[(size_t)r * 256 + c] = v;
      }
    }
  }
}

// ---------------- weight-prep mega-kernel (one dispatch) ----------------
__launch_bounds__(256)
__global__ void k_prep(const float* __restrict__ chebW, const float* __restrict__ W3,
                       u16* __restrict__ Wft, const float* __restrict__ chebB,
                       const float* __restrict__ b3, float* __restrict__ bf,
                       const float* __restrict__ W1, u16* __restrict__ W1t,
                       const float* __restrict__ W2, u16* __restrict__ W2t,
                       const float* __restrict__ W4, u16* __restrict__ W4t,
                       const float* __restrict__ W5, const float* __restrict__ W6,
                       const float* __restrict__ b5, const float* __restrict__ b6,
                       float* __restrict__ W56, float* __restrict__ b56,
                       const int* __restrict__ deg, float* __restrict__ dis, int N) {
  int b = blockIdx.x, t = threadIdx.x;
  if (b < 384) {
    int kk = b, c2 = t;
    int k = kk >> 7, r = kk & 127;
    float acc = 0.f;
    for (int j = 0; j < 512; ++j) {
      int i = j >> 7, cj = j & 127;
      float a = chebW[((size_t)((i * 3 + k) * 128 + r)) * 128 + cj];
      acc = fmaf(a, W3[(size_t)j * 256 + c2], acc);
    }
    Wft[(size_t)c2 * 384 + kk] = f2b(acc);
  } else if (b == 384) {
    int c2 = t;
    float acc = b3[c2];
    for (int j = 0; j < 512; ++j) {
      int i = j >> 7, cj = j & 127;
      acc = fmaf(chebB[i * 128 + cj], W3[(size_t)j * 256 + c2], acc);
    }
    bf[c2] = acc;
  } else if (b < 769) {
    int idx = (b - 385) * 256 + t;
    if (idx < 16384) {
      int n = idx >> 7, k = idx & 127;
      W1t[idx] = f2b(W1[(size_t)k * 128 + n]);
    } else if (idx < 32768) {
      int j = idx - 16384; int n = j >> 7, k = j & 127;
      W2t[j] = f2b(W2[(size_t)k * 128 + n]);
    } else {
      int j = idx - 32768; int n = j >> 8, k = j & 255;
      W4t[j] = f2b(W4[(size_t)k * 256 + n]);
    }
  } else if (b < 897) {
    int j = (b - 769) * 256 + t;
    int r = j >> 8, c = j & 255;
    float acc = 0.f;
    for (int k = 0; k < 256; ++k)
      acc = fmaf(W5[(size_t)r * 256 + k], W6[(size_t)k * 256 + c], acc);
    W56[j] = acc;
  } else if (b == 897) {
    int c = t;
    float acc = b6[c];
    for (int k = 0; k < 256; ++k)
      acc = fmaf(b5[k], W6[(size_t)k * 256 + c], acc);
    b56[c] = acc;
  } else {
    int base = (b - 898) * 1024 + t * 4;
    if (base + 3 < N) {
      int4 dv = *(const int4*)(deg + base);
      float4 dd;
      dd.x = dv.x > 0 ? rsqrtf((float)dv.x) : 0.f;
      dd.y = dv.y > 0 ? rsqrtf((float)dv.y) : 0.f;
      dd.z = dv.z > 0 ? rsqrtf((float)dv.z) : 0.f;
      dd.w = dv.w > 0 ? rsqrtf((float)dv.w) : 0.f;
      *(float4*)(dis + base) = dd;
    } else {
      for (int i = base; i < N; ++i) {
        int d = deg[i]; dis[i] = d > 0 ? rsqrtf((float)d) : 0.f;
      }
    }
  }
}

// ---------------- pooling / epilogue ----------------
__launch_bounds__(256)
__global__ void k_pool(const u16* __restrict__ h3, const float* __restrict__ tmp2,
                       const float* __restrict__ xlx2, float pw,
                       float* __restrict__ hc, int npg) {
  int g = blockIdx.x;
  int t = threadIdx.x;
  int lane = t & 63, w = t >> 6;
  const float* tp = tmp2 + (size_t)g * 256;
  float t0 = tp[lane], t1 = tp[64 + lane], t2 = tp[128 + lane], t3 = tp[192 + lane];
  float a0 = 0.f, a1 = 0.f, a2 = 0.f, a3 = 0.f;
  for (int idx = w; idx < npg; idx += 4) {
    const u16* hp = h3 + ((size_t)g * npg + idx) * 256;
    float v0 = b2f(hp[lane]), v1 = b2f(hp[64 + lane]);
    float v2 = b2f(hp[128 + lane]), v3 = b2f(hp[192 + lane]);
    float p = v0 * t0 + v1 * t1 + v2 * t2 + v3 * t3;
#pragma unroll
    for (int o = 1; o < 64; o <<= 1) p += __shfl_xor(p, o, 64);
    a0 = fmaf(p, v0, a0); a1 = fmaf(p, v1, a1);
    a2 = fmaf(p, v2, a2); a3 = fmaf(p, v3, a3);
  }
  __shared__ float red[4][256];
  red[w][lane] = a0; red[w][64 + lane] = a1;
  red[w][128 + lane] = a2; red[w][192 + lane] = a3;
  __syncthreads();
  float s = red[0][t] + red[1][t] + red[2][t] + red[3][t];
  hc[(size_t)g * 512 + t] = s * pw;
  hc[(size_t)g * 512 + 256 + t] = xlx2[(size_t)g * 256 + t];
}

__launch_bounds__(256)
__global__ void k_bnstats(const float* __restrict__ hc, float* __restrict__ mu,
                          float* __restrict__ rstd, int G) {
  int c = blockIdx.x;  // 512
  int t = threadIdx.x;
  float s = 0.f, s2 = 0.f;
  for (int g = t; g < G; g += 256) {
    float v = hc[(size_t)g * 512 + c];
    s += v; s2 = fmaf(v, v, s2);
  }
#pragma unroll
  for (int o = 1; o < 64; o <<= 1) { s += __shfl_xor(s, o, 64); s2 += __shfl_xor(s2, o, 64); }
  __shared__ float rs[4], rs2[4];
  int w = t >> 6, lane = t & 63;
  if (lane == 0) { rs[w] = s; rs2[w] = s2; }
  __syncthreads();
  if (t == 0) {
    float S = rs[0] + rs[1] + rs[2] + rs[3];
    float S2 = rs2[0] + rs2[1] + rs2[2] + rs2[3];
    float m = S / (float)G;
    float v = fmaxf(S2 / (float)G - m * m, 0.f);
    mu[c] = m;
    rstd[c] = rsqrtf(v + 1e-5f);
  }
}

__launch_bounds__(256)
__global__ void k_final(const float* __restrict__ hc, const float* __restrict__ mu,
                        const float* __restrict__ rstd, const float* __restrict__ gamma,
                        const float* __restrict__ beta, const float* __restrict__ W7,
                        const float* __restrict__ b7, float* __restrict__ out) {
  int g = blockIdx.x, t = threadIdx.x;
  int lane = t & 63, w = t >> 6;
  float p0 = 0.f, p1 = 0.f;
  for (int c = t; c < 512; c += 256) {
    float xn = fmaf(gamma[c] * (hc[(size_t)g * 512 + c] - mu[c]), rstd[c], beta[c]);
    p0 = fmaf(xn, W7[c * 2 + 0], p0);
    p1 = fmaf(xn, W7[c * 2 + 1], p1);
  }
#pragma unroll
  for (int o = 1; o < 64; o <<= 1) { p0 += __shfl_xor(p0, o, 64); p1 += __shfl_xor(p1, o, 64); }
  __shared__ float r0[4], r1[4];
  if (lane == 0) { r0[w] = p0; r1[w] = p1; }
  __syncthreads();
  if (t == 0) out[(size_t)g * 2 + 0] = r0[0] + r0[1] + r0[2] + r0[3] + b7[0];
  if (t == 1) out[(size_t)g * 2 + 1] = r1[0] + r1[1] + r1[2] + r1[3] + b7[1];
}

// ---------------------------------------------------------------------------

extern "C" void kernel_launch(void* const* d_in, const int* in_sizes, int n_in,
                              void* d_out, int out_size, void* d_ws, size_t ws_size,
                              hipStream_t stream) {
  const float* features = (const float*)d_in[0];
  const int* eidx = (const int*)d_in[1];
  const float* xlx = (const float*)d_in[3];
  const float* W1 = (const float*)d_in[4];  const float* b1 = (const float*)d_in[5];
  const float* W2 = (const float*)d_in[6];  const float* b2 = (const float*)d_in[7];
  const float* chebW = (const float*)d_in[8]; const float* chebB = (const float*)d_in[9];
  const float* W3 = (const float*)d_in[10]; const float* b3 = (const float*)d_in[11];
  const float* W4 = (const float*)d_in[12]; const float* b4 = (const float*)d_in[13];
  const float* W5 = (const float*)d_in[14]; const float* b5 = (const float*)d_in[15];
  const float* W6 = (const float*)d_in[16]; const float* b6 = (const float*)d_in[17];
  const float* W8 = (const float*)d_in[18]; const float* b8 = (const float*)d_in[19];
  const float* W9 = (const float*)d_in[20]; const float* b9 = (const float*)d_in[21];
  const float* W7 = (const float*)d_in[22]; const float* b7 = (const float*)d_in[23];
  const float* gamma = (const float*)d_in[24]; const float* beta = (const float*)d_in[25];

  const int N = in_sizes[0] / 128;  // 100000
  const int E = in_sizes[1] / 2;    // 600000
  const int G = in_sizes[3] / 128;  // 1000
  const int npg = N / G;            // 100

  const int* src = eidx;
  const int* dst = eidx + E;

  // ---- workspace layout ----
  uint8_t* base = (uint8_t*)d_ws;
  size_t off = 0;
  auto alloc = [&](size_t bytes) {
    uint8_t* p = base + off;
    off += (bytes + 255) & ~(size_t)255;
    return p;
  };
  size_t nbh = (size_t)N * 128;
  u16* T0b = (u16*)alloc(nbh * 2);
  u16* T1b = (u16*)alloc(nbh * 2);
  u16* T2b = (u16*)alloc(nbh * 2);
  u16* h3b = (u16*)alloc((size_t)N * 256 * 2);
  float* bf = (float*)alloc(256 * 4);
  u16* W1t = (u16*)alloc(128 * 128 * 2);
  u16* W2t = (u16*)alloc(128 * 128 * 2);
  u16* Wft = (u16*)alloc(256 * 384 * 2);
  u16* W4t = (u16*)alloc(256 * 256 * 2);
  float* W56 = (float*)alloc(128 * 256 * 4);
  float* b56 = (float*)alloc(256 * 4);
  float* dis = (float*)alloc((size_t)N * 4);
  float* S1 = (float*)alloc((size_t)G * 256 * 4);
  float* S2 = (float*)alloc((size_t)G * 256 * 4);
  float* S4 = (float*)alloc((size_t)G * 256 * 4);
  float* hc = (float*)alloc((size_t)G * 512 * 4);
  float* mu = (float*)alloc(512 * 4);
  float* rstd = (float*)alloc(512 * 4);
  size_t zoff = off;
  int* deg = (int*)alloc((size_t)N * 4);
  int* indeg = (int*)alloc((size_t)N * 4);
  size_t zlen = off - zoff;
  int* rowptr = (int*)alloc(((size_t)N + 1) * 4);
  int* rowcur = (int*)alloc((size_t)N * 4);
  int* csre = (int*)alloc((size_t)E * 4);
  int* bsum = (int*)alloc(260 * 4);
  int* boff = (int*)alloc(260 * 4);
  if (off > ws_size)
    fprintf(stderr, "WARNING: ws too small: need %zu have %zu\n", off, ws_size);

  hipMemsetAsync(base + zoff, 0, zlen, stream);

  // CSR build
  k_hist<<<(E + 255) / 256, 256, 0, stream>>>(dst, indeg, E);
  int B = (N + 1023) / 1024;  // 98; must be <= 256
  k_scan1<<<B, 256, 0, stream>>>(indeg, rowptr, bsum, N);
  k_scan2<<<1, 256, 0, stream>>>(bsum, boff, B);
  k_scan3<<<B, 256, 0, stream>>>(rowptr, boff, rowcur, N, B);
  k_scatter<<<(E + 255) / 256, 256, 0, stream>>>(src, dst, rowcur, deg, csre, E);

  // weight prep + dis (after scatter's deg histogram)
  k_prep<<<898 + B, 256, 0, stream>>>(chebW, W3, Wft, chebB, b3, bf,
                                      W1, W1t, W2, W2t, W4, W4t,
                                      W5, W6, b5, b6, W56, b56, deg, dis, N);

  // node MLP fused: T0 = act(act(F@W1+b1)@W2+b2)
  k_gemm12<<<(N + 63) / 64, 256, 0, stream>>>(features, N, W1t, b1, W2t, b2, T0b);

  // propagation via CSR gather (no atomics)
  int ggrid = (N + 3) / 4;
  k_gather<<<ggrid, 256, 0, stream>>>(T0b, rowptr, csre, dis, nullptr, 1.0f, T1b, N);
  k_gather<<<ggrid, 256, 0, stream>>>(T1b, rowptr, csre, dis, T0b, 2.0f, T2b, N);

  // fused: h3 = act(act([T0|T1|T2]@Wft + bf) @ W4 + b4)
  k_gemm34<<<(N + 63) / 64, 256, 0, stream>>>(T0b, T1b, T2b, N, Wft, bf,
                                              W4t, b4, h3b);

  // graph-level chains (G=1000, fp32, cheap); W5/W6 folded into W56
  {
    dim3 grid2(256 / 64, (G + 63) / 64, 2);
    k_gemm2w<<<grid2, 256, 0, stream>>>(xlx, G, W8, b8, S1, W56, b56, S4);
    dim3 grid(256 / 64, (G + 63) / 64);
    k_gemm<<<grid, 256, 0, stream>>>(S1, G, 256, W9, 256, b9, 1, S2);
  }

  k_pool<<<G, 256, 0, stream>>>(h3b, S2, S4, 1.0f / (float)npg, hc, npg);
  k_bnstats<<<512, 256, 0, stream>>>(hc, mu, rstd, G);
  k_final<<<G, 256, 0, stream>>>(hc, mu, rstd, gamma, beta, W7, b7, (float*)d_out);
}

// Round 12
// 473.682 us; speedup vs baseline: 1.1813x; 1.0075x over previous
//
#include <hip/hip_runtime.h>
#include <cstdio>
#include <cstdint>

// ---------------------------------------------------------------------------
// GADGNN forward. R12: gemm34 v4 — fp8 h2 exchange buffer (16 KB) + fp8 W4
// phase 2 (BK=64, half the barriers), 36 KB LDS -> 4 blocks/CU with the
// acc-dies-early liveness that keeps VGPR<=128 (R10 lesson). T2 algebra
// (2*prop(T1)-T0) folded into Wft so gather2 is a pure prop (no sub read).
//  - k_gemm12: GEMM1+GEMM2 fused, weights LDS-resident (barrier-free K-loop)
//  - dst-CSR gather, quarter-wave edge split (R11)
// ---------------------------------------------------------------------------

typedef unsigned short u16;
typedef unsigned char u8;
typedef __bf16 v8bf __attribute__((ext_vector_type(8)));
typedef float f32x4 __attribute__((ext_vector_type(4)));
typedef u16 u16x8 __attribute__((ext_vector_type(8)));

__device__ inline float b2f(u16 u) {
  union { unsigned int i; float f; } x; x.i = ((unsigned int)u) << 16; return x.f;
}
__device__ inline u16 f2b(float f) {  // RNE
  unsigned int u = __float_as_uint(f);
  unsigned int r = (u + 0x7fffu + ((u >> 16) & 1u)) >> 16;
  return (u16)r;
}
__device__ inline u8 f2fp8(float f) {  // fp8 e4m3 (OCP on gfx950), HW convert
  int p = __builtin_amdgcn_cvt_pk_fp8_f32(f, 0.f, 0, false);
  return (u8)(p & 0xff);
}

// async global->LDS, 16 B per lane; lds dest = base + lane*16 (wave-uniform base)
__device__ __forceinline__ void glds16(const u16* g, u16* l) {
  __builtin_amdgcn_global_load_lds(
      (const __attribute__((address_space(1))) void*)g,
      (__attribute__((address_space(3))) void*)l, 16, 0, 0);
}
__device__ __forceinline__ void glds16b(const u8* g, u8* l) {
  __builtin_amdgcn_global_load_lds(
      (const __attribute__((address_space(1))) void*)g,
      (__attribute__((address_space(3))) void*)l, 16, 0, 0);
}

// ---------------- prep kernels ----------------

__global__ void k_hist(const int* __restrict__ dst, int* __restrict__ indeg, int E) {
  int e = blockIdx.x * blockDim.x + threadIdx.x;
  if (e < E) atomicAdd(&indeg[dst[e]], 1);
}

__launch_bounds__(256)
__global__ void k_scan1(const int* __restrict__ indeg, int* __restrict__ rowptr,
                        int* __restrict__ bsum, int N) {
  int b = blockIdx.x, t = threadIdx.x;
  int base = b * 1024 + t * 4;
  int4 v = make_int4(0, 0, 0, 0);
  if (base + 3 < N) v = *(const int4*)(indeg + base);
  else if (base < N) {
    v.x = indeg[base];
    v.y = base + 1 < N ? indeg[base + 1] : 0;
    v.z = base + 2 < N ? indeg[base + 2] : 0;
  }
  int s = v.x + v.y + v.z + v.w;
  int lane = t & 63, w = t >> 6;
  int inc = s;
#pragma unroll
  for (int o = 1; o < 64; o <<= 1) { int u = __shfl_up(inc, o, 64); if (lane >= o) inc += u; }
  __shared__ int wsum[4];
  if (lane == 63) wsum[w] = inc;
  __syncthreads();
  int woff = 0;
#pragma unroll
  for (int i = 0; i < 4; ++i) if (i < w) woff += wsum[i];
  int excl = woff + inc - s;
  int4 o4;
  o4.x = excl; o4.y = o4.x + v.x; o4.z = o4.y + v.y; o4.w = o4.z + v.z;
  if (base + 3 < N) *(int4*)(rowptr + base) = o4;
  else if (base < N) {
    rowptr[base] = o4.x;
    if (base + 1 < N) rowptr[base + 1] = o4.y;
    if (base + 2 < N) rowptr[base + 2] = o4.z;
  }
  if (t == 255) bsum[b] = woff + inc;
}

__launch_bounds__(256)
__global__ void k_scan2(const int* __restrict__ bsum, int* __restrict__ boff, int B) {
  int t = threadIdx.x;
  int v = t < B ? bsum[t] : 0;
  int lane = t & 63, w = t >> 6;
  int inc = v;
#pragma unroll
  for (int o = 1; o < 64; o <<= 1) { int u = __shfl_up(inc, o, 64); if (lane >= o) inc += u; }
  __shared__ int wsum[4];
  if (lane == 63) wsum[w] = inc;
  __syncthreads();
  int woff = 0;
#pragma unroll
  for (int i = 0; i < 4; ++i) if (i < w) woff += wsum[i];
  if (t < B) boff[t] = woff + inc - v;
  if (t == 255) boff[B] = woff + inc;
}

__launch_bounds__(256)
__global__ void k_scan3(int* __restrict__ rowptr, const int* __restrict__ boff,
                        int* __restrict__ rowcur, int N, int B) {
  int b = blockIdx.x, t = threadIdx.x;
  int base = b * 1024 + t * 4;
  int add = boff[b];
  if (base + 3 < N) {
    int4 v = *(const int4*)(rowptr + base);
    v.x += add; v.y += add; v.z += add; v.w += add;
    *(int4*)(rowptr + base) = v;
    *(int4*)(rowcur + base) = v;
  } else if (base < N) {
    for (int i = base; i < N; ++i) { int v = rowptr[i] + add; rowptr[i] = v; rowcur[i] = v; }
  }
  if (b == 0 && t == 0) rowptr[N] = boff[B];
}

// scatter edges into CSR slots + out-degree histogram
__global__ void k_scatter(const int* __restrict__ src, const int* __restrict__ dst,
                          int* __restrict__ rowcur, int* __restrict__ deg,
                          int* __restrict__ csre, int E) {
  int e = blockIdx.x * blockDim.x + threadIdx.x;
  if (e >= E) return;
  int s = src[e];
  atomicAdd(&deg[s], 1);
  int p = atomicAdd(&rowcur[dst[e]], 1);
  csre[p] = s;
}

// out[d,:] = (-scale*dis[d]) * sum_e dis[s_e]*x[s_e,:]  (- sub[d,:] if sub)
// quarter-wave edge split (R11): 16 lanes x 16B per row, unroll-2.
__launch_bounds__(256)
__global__ void k_gather(const u16* __restrict__ x, const int* __restrict__ rowptr,
                         const int* __restrict__ csre, const float* __restrict__ dis,
                         const u16* __restrict__ sub, float scale,
                         u16* __restrict__ out, int N) {
  int node = blockIdx.x * 4 + (threadIdx.x >> 6);
  if (node >= N) return;
  int lane = threadIdx.x & 63;
  int q = lane >> 4, ql = lane & 15;
  int fo = ql * 8;
  int b = rowptr[node], e = rowptr[node + 1];
  float a[8] = {0.f, 0.f, 0.f, 0.f, 0.f, 0.f, 0.f, 0.f};
  int i = b + q;
  for (; i + 4 < e; i += 8) {
    int s0 = csre[i], s1 = csre[i + 4];
    u16x8 v0 = *(const u16x8*)(x + (size_t)s0 * 128 + fo);
    u16x8 v1 = *(const u16x8*)(x + (size_t)s1 * 128 + fo);
    float w0 = dis[s0], w1 = dis[s1];
#pragma unroll
    for (int j = 0; j < 8; ++j) {
      a[j] = fmaf(w0, b2f(v0[j]), a[j]);
      a[j] = fmaf(w1, b2f(v1[j]), a[j]);
    }
  }
  if (i < e) {
    int s = csre[i];
    u16x8 v = *(const u16x8*)(x + (size_t)s * 128 + fo);
    float w = dis[s];
#pragma unroll
    for (int j = 0; j < 8; ++j) a[j] = fmaf(w, b2f(v[j]), a[j]);
  }
#pragma unroll
  for (int o = 16; o < 64; o <<= 1)
#pragma unroll
    for (int j = 0; j < 8; ++j) a[j] += __shfl_xor(a[j], o, 64);
  if (q == 0) {
    float m = -scale * dis[node];
    u16x8 o8;
    if (sub) {
      u16x8 sv = *(const u16x8*)(sub + (size_t)node * 128 + fo);
#pragma unroll
      for (int j = 0; j < 8; ++j) o8[j] = f2b(a[j] * m - b2f(sv[j]));
    } else {
#pragma unroll
      for (int j = 0; j < 8; ++j) o8[j] = f2b(a[j] * m);
    }
    *(u16x8*)(out + (size_t)node * 128 + fo) = o8;
  }
}

// ---------------- fused GEMM1+GEMM2, weights LDS-resident ----------------
__launch_bounds__(256, 3)
__global__ void k_gemm12(const float* __restrict__ F, int M,
                         const u16* __restrict__ W1t, const float* __restrict__ b1,
                         const u16* __restrict__ W2t, const float* __restrict__ b2,
                         u16* __restrict__ C) {
  __shared__ u16 Wsl[128][128];  // 32 KB, 8-group XOR swizzle
  __shared__ u16 Hsl[64][136];   // 17 KB: A-tile (bf16) then h1-tile
  int t = threadIdx.x;
  int wave = t >> 6, lane = t & 63;
  int quad = lane >> 4, l16 = lane & 15;
  int row0 = blockIdx.x * 64;
  int lg16 = lane & 15;

  {
    int r = t >> 2, q = t & 3;
    int grow = min(row0 + r, M - 1);
#pragma unroll
    for (int j = 0; j < 4; ++j) {
      float4 f0 = *(const float4*)(F + (size_t)grow * 128 + q * 32 + j * 8);
      float4 f1 = *(const float4*)(F + (size_t)grow * 128 + q * 32 + j * 8 + 4);
      u16x8 av;
      av[0] = f2b(f0.x); av[1] = f2b(f0.y); av[2] = f2b(f0.z); av[3] = f2b(f0.w);
      av[4] = f2b(f1.x); av[5] = f2b(f1.y); av[6] = f2b(f1.z); av[7] = f2b(f1.w);
      *(u16x8*)&Hsl[r][q * 32 + j * 8] = av;
    }
  }
#pragma unroll
  for (int i = 0; i < 8; ++i) {
    int rbase = wave * 32 + i * 4;
    int wrow = rbase + (lane >> 4);
    int grp = lg16 ^ (wrow & 7);
    glds16(W1t + (size_t)wrow * 128 + grp * 8, &Wsl[rbase][0]);
  }
  __syncthreads();

  f32x4 zero = {0.f, 0.f, 0.f, 0.f};
  f32x4 acc[4][2];
#pragma unroll
  for (int i = 0; i < 4; ++i) { acc[i][0] = zero; acc[i][1] = zero; }

#pragma unroll
  for (int c = 0; c < 4; ++c) {
    v8bf a_frag[4], b_frag[2];
#pragma unroll
    for (int rt = 0; rt < 4; ++rt)
      a_frag[rt] = *(const v8bf*)&Hsl[rt * 16 + l16][c * 32 + quad * 8];
#pragma unroll
    for (int ct = 0; ct < 2; ++ct) {
      int col = wave * 32 + ct * 16 + l16;
      int g = (c * 4 + quad) ^ (col & 7);
      b_frag[ct] = *(const v8bf*)&Wsl[col][g * 8];
    }
#pragma unroll
    for (int rt = 0; rt < 4; ++rt)
#pragma unroll
      for (int ct = 0; ct < 2; ++ct)
        acc[rt][ct] = __builtin_amdgcn_mfma_f32_16x16x32_bf16(
            a_frag[rt], b_frag[ct], acc[rt][ct], 0, 0, 0);
  }
  __syncthreads();

  {
    float bb0 = b1[wave * 32 + l16], bb1 = b1[wave * 32 + 16 + l16];
#pragma unroll
    for (int rt = 0; rt < 4; ++rt)
#pragma unroll
      for (int ct = 0; ct < 2; ++ct) {
        int col = wave * 32 + ct * 16 + l16;
        float bb = ct ? bb1 : bb0;
#pragma unroll
        for (int r = 0; r < 4; ++r) {
          int row = rt * 16 + quad * 4 + r;
          float v = acc[rt][ct][r] + bb;
          v = v > 0.f ? v : 0.01f * v;
          Hsl[row][col] = f2b(v);
        }
      }
  }
#pragma unroll
  for (int i = 0; i < 8; ++i) {
    int rbase = wave * 32 + i * 4;
    int wrow = rbase + (lane >> 4);
    int grp = lg16 ^ (wrow & 7);
    glds16(W2t + (size_t)wrow * 128 + grp * 8, &Wsl[rbase][0]);
  }
  __syncthreads();

  f32x4 acc2[4][2];
#pragma unroll
  for (int i = 0; i < 4; ++i) { acc2[i][0] = zero; acc2[i][1] = zero; }

#pragma unroll
  for (int c = 0; c < 4; ++c) {
    v8bf a_frag[4], b_frag[2];
#pragma unroll
    for (int rt = 0; rt < 4; ++rt)
      a_frag[rt] = *(const v8bf*)&Hsl[rt * 16 + l16][c * 32 + quad * 8];
#pragma unroll
    for (int ct = 0; ct < 2; ++ct) {
      int col = wave * 32 + ct * 16 + l16;
      int g = (c * 4 + quad) ^ (col & 7);
      b_frag[ct] = *(const v8bf*)&Wsl[col][g * 8];
    }
#pragma unroll
    for (int rt = 0; rt < 4; ++rt)
#pragma unroll
      for (int ct = 0; ct < 2; ++ct)
        acc2[rt][ct] = __builtin_amdgcn_mfma_f32_16x16x32_bf16(
            a_frag[rt], b_frag[ct], acc2[rt][ct], 0, 0, 0);
  }
  {
    float bb0 = b2[wave * 32 + l16], bb1 = b2[wave * 32 + 16 + l16];
#pragma unroll
    for (int rt = 0; rt < 4; ++rt)
#pragma unroll
      for (int ct = 0; ct < 2; ++ct) {
        int col = wave * 32 + ct * 16 + l16;
        float bb = ct ? bb1 : bb0;
#pragma unroll
        for (int r = 0; r < 4; ++r) {
          int row = row0 + rt * 16 + quad * 4 + r;
          if (row < M) {
            float v = acc2[rt][ct][r] + bb;
            v = v > 0.f ? v : 0.01f * v;
            C[(size_t)row * 128 + col] = f2b(v);
          }
        }
      }
  }
}

// ---------------- fused GEMM3+GEMM4 v4 (36 KB LDS, 4 blocks/CU) --------------
// Phase 1 (bf16, BK=32): h2[64,256] = [T0|T1|P] @ Wft' (T2 algebra folded into
// Wft'). Phase 2 (fp8, BK=64): h3 = leaky(h2_fp8 @ W4_fp8 + b4). acc dies at
// the h2 write -> VGPR fits the 128/wave budget at 4 blocks/CU (R10 lesson).
__launch_bounds__(256, 4)
__global__ void k_gemm34(const u16* __restrict__ A0, const u16* __restrict__ A1,
                         const u16* __restrict__ A2, int M,
                         const u16* __restrict__ Wft, const float* __restrict__ bf,
                         const u8* __restrict__ W4t8, const float* __restrict__ b4,
                         u16* __restrict__ C) {
  __shared__ u8 smem[36864];
  u16 (*Asl)[32] = (u16(*)[32])smem;              // [64][32] bf16, 4 KB
  u16 (*Bsl)[32] = (u16(*)[32])(smem + 4096);     // [256][32] bf16, 16 KB (phase 1)
  u8 (*Bsl8)[64] = (u8(*)[64])(smem + 4096);      // [256][64] fp8 (phase 2, aliases Bsl)
  u8 (*h2sl)[256] = (u8(*)[256])(smem + 20480);   // [64][256] fp8, 16 KB
  int t = threadIdx.x;
  int wave = t >> 6, lane = t & 63;
  int quad = lane >> 4, l16 = lane & 15;
  int row0 = blockIdx.x * 64;
  int lrow = lane >> 2, lg = lane & 3;
  int sgg = lg ^ ((lrow >> 1) & 3);
  int rgs = quad ^ ((l16 >> 1) & 3);

  f32x4 zero = {0.f, 0.f, 0.f, 0.f};
  f32x4 acc[4][4];
#pragma unroll
  for (int i = 0; i < 4; ++i)
#pragma unroll
    for (int j = 0; j < 4; ++j) acc[i][j] = zero;

  // phase 1: h2[64,256] = [T0|T1|P] @ Wft'
  for (int k0 = 0; k0 < 384; k0 += 32) {
    const u16* Ap = k0 < 128 ? A0 : (k0 < 256 ? A1 : A2);
    int kc = k0 & 127;
    {
      int grow = min(row0 + wave * 16 + lrow, M - 1);
      glds16(Ap + (size_t)grow * 128 + kc + sgg * 8, &Asl[wave * 16][0]);
    }
#pragma unroll
    for (int i = 0; i < 4; ++i)
      glds16(Wft + (size_t)(wave * 64 + i * 16 + lrow) * 384 + k0 + sgg * 8,
             &Bsl[wave * 64 + i * 16][0]);
    __syncthreads();
    v8bf a_frag[4], b_frag[4];
#pragma unroll
    for (int rt = 0; rt < 4; ++rt)
      a_frag[rt] = *(const v8bf*)&Asl[rt * 16 + l16][rgs * 8];
#pragma unroll
    for (int ct = 0; ct < 4; ++ct)
      b_frag[ct] = *(const v8bf*)&Bsl[wave * 64 + ct * 16 + l16][rgs * 8];
#pragma unroll
    for (int rt = 0; rt < 4; ++rt)
#pragma unroll
      for (int ct = 0; ct < 4; ++ct)
        acc[rt][ct] = __builtin_amdgcn_mfma_f32_16x16x32_bf16(
            a_frag[rt], b_frag[ct], acc[rt][ct], 0, 0, 0);
    __syncthreads();
  }

  // write leaky(h2 + bf) into h2sl as fp8 (row-XOR swizzled 8B groups)
  {
    float bb0 = bf[wave * 64 + l16], bb1 = bf[wave * 64 + 16 + l16];
    float bb2 = bf[wave * 64 + 32 + l16], bb3 = bf[wave * 64 + 48 + l16];
    float bbs[4] = {bb0, bb1, bb2, bb3};
#pragma unroll
    for (int rt = 0; rt < 4; ++rt)
#pragma unroll
      for (int ct = 0; ct < 4; ++ct) {
        int col = wave * 64 + ct * 16 + l16;
#pragma unroll
        for (int r = 0; r < 4; ++r) {
          int row = rt * 16 + quad * 4 + r;
          float v = acc[rt][ct][r] + bbs[ct];
          v = v > 0.f ? v : 0.01f * v;
          int pg = (col >> 3) ^ (row & 31);
          h2sl[row][(pg << 3) | (col & 7)] = f2fp8(v);
        }
      }
  }
  __syncthreads();

  f32x4 acc2[4][4];
#pragma unroll
  for (int i = 0; i < 4; ++i)
#pragma unroll
    for (int j = 0; j < 4; ++j) acc2[i][j] = zero;

  // phase 2: h3 = leaky(h2) @ W4, fp8 x fp8, BK=64 (4 steps)
  for (int k0 = 0; k0 < 256; k0 += 64) {
#pragma unroll
    for (int i = 0; i < 4; ++i) {
      int c = wave * 64 + i * 16 + (lane >> 2);
      int s = (c & 3) ^ ((c >> 2) & 3);
      glds16b(W4t8 + (size_t)c * 256 + k0 + (((lane & 3) ^ s) << 4),
              &Bsl8[wave * 64 + i * 16][0]);
    }
    __syncthreads();
#pragma unroll
    for (int sub = 0; sub < 64; sub += 32) {
      long a8[4], b8[4];
#pragma unroll
      for (int rt = 0; rt < 4; ++rt) {
        int r = rt * 16 + l16;
        int g = ((k0 + sub) >> 3) + quad;  // logical 8B group (0..31)
        int pg = g ^ (r & 31);
        a8[rt] = *(const long*)&h2sl[r][pg << 3];
      }
#pragma unroll
      for (int ct = 0; ct < 4; ++ct) {
        int c = wave * 64 + ct * 16 + l16;
        int s = (c & 3) ^ ((c >> 2) & 3);
        int off = sub + quad * 8;          // 0..63 within 64B row slice
        int pj = (off >> 4) ^ s;
        b8[ct] = *(const long*)&Bsl8[c][(pj << 4) | (off & 15)];
      }
#pragma unroll
      for (int rt = 0; rt < 4; ++rt)
#pragma unroll
        for (int ct = 0; ct < 4; ++ct)
          acc2[rt][ct] = __builtin_amdgcn_mfma_f32_16x16x32_fp8_fp8(
              a8[rt], b8[ct], acc2[rt][ct], 0, 0, 0);
    }
    __syncthreads();
  }
  {
    float bb0 = b4[wave * 64 + l16], bb1 = b4[wave * 64 + 16 + l16];
    float bb2 = b4[wave * 64 + 32 + l16], bb3 = b4[wave * 64 + 48 + l16];
    float bbs[4] = {bb0, bb1, bb2, bb3};
#pragma unroll
    for (int rt = 0; rt < 4; ++rt)
#pragma unroll
      for (int ct = 0; ct < 4; ++ct) {
        int col = wave * 64 + ct * 16 + l16;
#pragma unroll
        for (int r = 0; r < 4; ++r) {
          int row = row0 + rt * 16 + quad * 4 + r;
          if (row < M) {
            float v = acc2[rt][ct][r] + bbs[ct];
            v = v > 0.f ? v : 0.01f * v;
            C[(size_t)row * 256 + col] = f2b(v);
          }
        }
      }
  }
}

// ---------------- fp32 tiled GEMM (graph-level, tiny) ----------------
__launch_bounds__(256)
__global__ void k_gemm(const float* __restrict__ A0, int M, int K,
                       const float* __restrict__ B, int Nc,
                       const float* __restrict__ bias, int act,
                       float* __restrict__ C) {
  __shared__ float As[16][68];
  __shared__ float Bs[16][68];
  int t = threadIdx.x;
  int tx = t & 15, ty = t >> 4;
  int row0 = blockIdx.y * 64, col0 = blockIdx.x * 64;
  int ar = t >> 2, ac4 = (t & 3) << 2;
  int br = t >> 4, bc4 = (t & 15) << 2;
  float acc[4][4] = {{0.f}};
  for (int k0 = 0; k0 < K; k0 += 16) {
    int arow = row0 + ar;
    float4 av = make_float4(0.f, 0.f, 0.f, 0.f);
    if (arow < M) av = *(const float4*)(A0 + (size_t)arow * K + k0 + ac4);
    As[ac4 + 0][ar] = av.x; As[ac4 + 1][ar] = av.y;
    As[ac4 + 2][ar] = av.z; As[ac4 + 3][ar] = av.w;
    float4 bv = *(const float4*)(B + (size_t)(k0 + br) * Nc + col0 + bc4);
    *(float4*)&Bs[br][bc4] = bv;
    __syncthreads();
#pragma unroll
    for (int kk = 0; kk < 16; ++kk) {
      float4 a4 = *(const float4*)&As[kk][ty << 2];
      float4 b4 = *(const float4*)&Bs[kk][tx << 2];
      float a[4] = {a4.x, a4.y, a4.z, a4.w};
      float b[4] = {b4.x, b4.y, b4.z, b4.w};
#pragma unroll
      for (int i = 0; i < 4; ++i)
#pragma unroll
        for (int j = 0; j < 4; ++j) acc[i][j] = fmaf(a[i], b[j], acc[i][j]);
    }
    __syncthreads();
  }
#pragma unroll
  for (int i = 0; i < 4; ++i) {
    int r = row0 + (ty << 2) + i;
    if (r < M) {
#pragma unroll
      for (int j = 0; j < 4; ++j) {
        int c = col0 + (tx << 2) + j;
        float v = acc[i][j];
        if (bias) v += bias[c];
        if (act) v = v > 0.f ? v : 0.01f * v;
        C[(size_t)r * Nc + c] = v;
      }
    }
  }
}

// two independent 128->256 graph GEMMs sharing A; blockIdx.z selects weights.
__launch_bounds__(256)
__global__ void k_gemm2w(const float* __restrict__ A0, int M,
                         const float* __restrict__ B0, const float* __restrict__ bias0,
                         float* __restrict__ C0,
                         const float* __restrict__ B1, const float* __restrict__ bias1,
                         float* __restrict__ C1) {
  const float* B = blockIdx.z ? B1 : B0;
  const float* bias = blockIdx.z ? bias1 : bias0;
  float* C = blockIdx.z ? C1 : C0;
  __shared__ float As[16][68];
  __shared__ float Bs[16][68];
  int t = threadIdx.x;
  int tx = t & 15, ty = t >> 4;
  int row0 = blockIdx.y * 64, col0 = blockIdx.x * 64;
  int ar = t >> 2, ac4 = (t & 3) << 2;
  int br = t >> 4, bc4 = (t & 15) << 2;
  float acc[4][4] = {{0.f}};
  for (int k0 = 0; k0 < 128; k0 += 16) {
    int arow = row0 + ar;
    float4 av = make_float4(0.f, 0.f, 0.f, 0.f);
    if (arow < M) av = *(const float4*)(A0 + (size_t)arow * 128 + k0 + ac4);
    As[ac4 + 0][ar] = av.x; As[ac4 + 1][ar] = av.y;
    As[ac4 + 2][ar] = av.z; As[ac4 + 3][ar] = av.w;
    float4 bv = *(const float4*)(B + (size_t)(k0 + br) * 256 + col0 + bc4);
    *(float4*)&Bs[br][bc4] = bv;
    __syncthreads();
#pragma unroll
    for (int kk = 0; kk < 16; ++kk) {
      float4 a4 = *(const float4*)&As[kk][ty << 2];
      float4 b4 = *(const float4*)&Bs[kk][tx << 2];
      float a[4] = {a4.x, a4.y, a4.z, a4.w};
      float b[4] = {b4.x, b4.y, b4.z, b4.w};
#pragma unroll
      for (int i = 0; i < 4; ++i)
#pragma unroll
        for (int j = 0; j < 4; ++j) acc[i][j] = fmaf(a[i], b[j], acc[i][j]);
    }
    __syncthreads();
  }
#pragma unroll
  for (int i = 0; i < 4; ++i) {
    int r = row0 + (ty << 2) + i;
    if (r < M) {
#pragma unroll
      for (int j = 0; j < 4; ++j) {
        int c = col0 + (tx << 2) + j;
        float v = acc[i][j] + bias[c];
        v = v > 0.f ? v : 0.01f * v;
        C[(size_t)r * 256 + c] = v;
      }
    }
  }
}

// ---------------- weight-prep mega-kernel (one dispatch) ----------------
// 0..127: Wft' (T2 algebra folded: Wf0-Wf2 | Wf1 | 2*Wf2); 128: bfuse;
// 129..512: W1t/W2t/W4t8; 513..640: W56; 641: b56; 642..: dis
__launch_bounds__(256)
__global__ void k_prep(const float* __restrict__ chebW, const float* __restrict__ W3,
                       u16* __restrict__ Wft, const float* __restrict__ chebB,
                       const float* __restrict__ b3, float* __restrict__ bf,
                       const float* __restrict__ W1, u16* __restrict__ W1t,
                       const float* __restrict__ W2, u16* __restrict__ W2t,
                       const float* __restrict__ W4, u8* __restrict__ W4t8,
                       const float* __restrict__ W5, const float* __restrict__ W6,
                       const float* __restrict__ b5, const float* __restrict__ b6,
                       float* __restrict__ W56, float* __restrict__ b56,
                       const int* __restrict__ deg, float* __restrict__ dis, int N) {
  int b = blockIdx.x, t = threadIdx.x;
  if (b < 128) {
    int r = b, c2 = t;
    float a0 = 0.f, a1 = 0.f, a2 = 0.f;
    for (int j = 0; j < 512; ++j) {
      int i = j >> 7, cj = j & 127;
      float w3v = W3[(size_t)j * 256 + c2];
      a0 = fmaf(chebW[((size_t)((i * 3 + 0) * 128 + r)) * 128 + cj], w3v, a0);
      a1 = fmaf(chebW[((size_t)((i * 3 + 1) * 128 + r)) * 128 + cj], w3v, a1);
      a2 = fmaf(chebW[((size_t)((i * 3 + 2) * 128 + r)) * 128 + cj], w3v, a2);
    }
    Wft[(size_t)c2 * 384 + r] = f2b(a0 - a2);
    Wft[(size_t)c2 * 384 + 128 + r] = f2b(a1);
    Wft[(size_t)c2 * 384 + 256 + r] = f2b(2.f * a2);
  } else if (b == 128) {
    int c2 = t;
    float acc = b3[c2];
    for (int j = 0; j < 512; ++j) {
      int i = j >> 7, cj = j & 127;
      acc = fmaf(chebB[i * 128 + cj], W3[(size_t)j * 256 + c2], acc);
    }
    bf[c2] = acc;
  } else if (b < 513) {
    int idx = (b - 129) * 256 + t;
    if (idx < 16384) {
      int n = idx >> 7, k = idx & 127;
      W1t[idx] = f2b(W1[(size_t)k * 128 + n]);
    } else if (idx < 32768) {
      int j = idx - 16384; int n = j >> 7, k = j & 127;
      W2t[j] = f2b(W2[(size_t)k * 128 + n]);
    } else {
      int j = idx - 32768; int n = j >> 8, k = j & 255;
      W4t8[j] = f2fp8(W4[(size_t)k * 256 + n]);
    }
  } else if (b < 641) {
    int j = (b - 513) * 256 + t;
    int r = j >> 8, c = j & 255;
    float acc = 0.f;
    for (int k = 0; k < 256; ++k)
      acc = fmaf(W5[(size_t)r * 256 + k], W6[(size_t)k * 256 + c], acc);
    W56[j] = acc;
  } else if (b == 641) {
    int c = t;
    float acc = b6[c];
    for (int k = 0; k < 256; ++k)
      acc = fmaf(b5[k], W6[(size_t)k * 256 + c], acc);
    b56[c] = acc;
  } else {
    int base = (b - 642) * 1024 + t * 4;
    if (base + 3 < N) {
      int4 dv = *(const int4*)(deg + base);
      float4 dd;
      dd.x = dv.x > 0 ? rsqrtf((float)dv.x) : 0.f;
      dd.y = dv.y > 0 ? rsqrtf((float)dv.y) : 0.f;
      dd.z = dv.z > 0 ? rsqrtf((float)dv.z) : 0.f;
      dd.w = dv.w > 0 ? rsqrtf((float)dv.w) : 0.f;
      *(float4*)(dis + base) = dd;
    } else {
      for (int i = base; i < N; ++i) {
        int d = deg[i]; dis[i] = d > 0 ? rsqrtf((float)d) : 0.f;
      }
    }
  }
}

// ---------------- pooling / epilogue ----------------
__launch_bounds__(256)
__global__ void k_pool(const u16* __restrict__ h3, const float* __restrict__ tmp2,
                       const float* __restrict__ xlx2, float pw,
                       float* __restrict__ hc, int npg) {
  int g = blockIdx.x;
  int t = threadIdx.x;
  int lane = t & 63, w = t >> 6;
  const float* tp = tmp2 + (size_t)g * 256;
  float t0 = tp[lane], t1 = tp[64 + lane], t2 = tp[128 + lane], t3 = tp[192 + lane];
  float a0 = 0.f, a1 = 0.f, a2 = 0.f, a3 = 0.f;
  for (int idx = w; idx < npg; idx += 4) {
    const u16* hp = h3 + ((size_t)g * npg + idx) * 256;
    float v0 = b2f(hp[lane]), v1 = b2f(hp[64 + lane]);
    float v2 = b2f(hp[128 + lane]), v3 = b2f(hp[192 + lane]);
    float p = v0 * t0 + v1 * t1 + v2 * t2 + v3 * t3;
#pragma unroll
    for (int o = 1; o < 64; o <<= 1) p += __shfl_xor(p, o, 64);
    a0 = fmaf(p, v0, a0); a1 = fmaf(p, v1, a1);
    a2 = fmaf(p, v2, a2); a3 = fmaf(p, v3, a3);
  }
  __shared__ float red[4][256];
  red[w][lane] = a0; red[w][64 + lane] = a1;
  red[w][128 + lane] = a2; red[w][192 + lane] = a3;
  __syncthreads();
  float s = red[0][t] + red[1][t] + red[2][t] + red[3][t];
  hc[(size_t)g * 512 + t] = s * pw;
  hc[(size_t)g * 512 + 256 + t] = xlx2[(size_t)g * 256 + t];
}

__launch_bounds__(256)
__global__ void k_bnstats(const float* __restrict__ hc, float* __restrict__ mu,
                          float* __restrict__ rstd, int G) {
  int c = blockIdx.x;  // 512
  int t = threadIdx.x;
  float s = 0.f, s2 = 0.f;
  for (int g = t; g < G; g += 256) {
    float v = hc[(size_t)g * 512 + c];
    s += v; s2 = fmaf(v, v, s2);
  }
#pragma unroll
  for (int o = 1; o < 64; o <<= 1) { s += __shfl_xor(s, o, 64); s2 += __shfl_xor(s2, o, 64); }
  __shared__ float rs[4], rs2[4];
  int w = t >> 6, lane = t & 63;
  if (lane == 0) { rs[w] = s; rs2[w] = s2; }
  __syncthreads();
  if (t == 0) {
    float S = rs[0] + rs[1] + rs[2] + rs[3];
    float S2 = rs2[0] + rs2[1] + rs2[2] + rs2[3];
    float m = S / (float)G;
    float v = fmaxf(S2 / (float)G - m * m, 0.f);
    mu[c] = m;
    rstd[c] = rsqrtf(v + 1e-5f);
  }
}

__launch_bounds__(256)
__global__ void k_final(const float* __restrict__ hc, const float* __restrict__ mu,
                        const float* __restrict__ rstd, const float* __restrict__ gamma,
                        const float* __restrict__ beta, const float* __restrict__ W7,
                        const float* __restrict__ b7, float* __restrict__ out) {
  int g = blockIdx.x, t = threadIdx.x;
  int lane = t & 63, w = t >> 6;
  float p0 = 0.f, p1 = 0.f;
  for (int c = t; c < 512; c += 256) {
    float xn = fmaf(gamma[c] * (hc[(size_t)g * 512 + c] - mu[c]), rstd[c], beta[c]);
    p0 = fmaf(xn, W7[c * 2 + 0], p0);
    p1 = fmaf(xn, W7[c * 2 + 1], p1);
  }
#pragma unroll
  for (int o = 1; o < 64; o <<= 1) { p0 += __shfl_xor(p0, o, 64); p1 += __shfl_xor(p1, o, 64); }
  __shared__ float r0[4], r1[4];
  if (lane == 0) { r0[w] = p0; r1[w] = p1; }
  __syncthreads();
  if (t == 0) out[(size_t)g * 2 + 0] = r0[0] + r0[1] + r0[2] + r0[3] + b7[0];
  if (t == 1) out[(size_t)g * 2 + 1] = r1[0] + r1[1] + r1[2] + r1[3] + b7[1];
}

// ---------------------------------------------------------------------------

extern "C" void kernel_launch(void* const* d_in, const int* in_sizes, int n_in,
                              void* d_out, int out_size, void* d_ws, size_t ws_size,
                              hipStream_t stream) {
  const float* features = (const float*)d_in[0];
  const int* eidx = (const int*)d_in[1];
  const float* xlx = (const float*)d_in[3];
  const float* W1 = (const float*)d_in[4];  const float* b1 = (const float*)d_in[5];
  const float* W2 = (const float*)d_in[6];  const float* b2 = (const float*)d_in[7];
  const float* chebW = (const float*)d_in[8]; const float* chebB = (const float*)d_in[9];
  const float* W3 = (const float*)d_in[10]; const float* b3 = (const float*)d_in[11];
  const float* W4 = (const float*)d_in[12]; const float* b4 = (const float*)d_in[13];
  const float* W5 = (const float*)d_in[14]; const float* b5 = (const float*)d_in[15];
  const float* W6 = (const float*)d_in[16]; const float* b6 = (const float*)d_in[17];
  const float* W8 = (const float*)d_in[18]; const float* b8 = (const float*)d_in[19];
  const float* W9 = (const float*)d_in[20]; const float* b9 = (const float*)d_in[21];
  const float* W7 = (const float*)d_in[22]; const float* b7 = (const float*)d_in[23];
  const float* gamma = (const float*)d_in[24]; const float* beta = (const float*)d_in[25];

  const int N = in_sizes[0] / 128;  // 100000
  const int E = in_sizes[1] / 2;    // 600000
  const int G = in_sizes[3] / 128;  // 1000
  const int npg = N / G;            // 100

  const int* src = eidx;
  const int* dst = eidx + E;

  // ---- workspace layout ----
  uint8_t* base = (uint8_t*)d_ws;
  size_t off = 0;
  auto alloc = [&](size_t bytes) {
    uint8_t* p = base + off;
    off += (bytes + 255) & ~(size_t)255;
    return p;
  };
  size_t nbh = (size_t)N * 128;
  u16* T0b = (u16*)alloc(nbh * 2);
  u16* T1b = (u16*)alloc(nbh * 2);
  u16* T2b = (u16*)alloc(nbh * 2);   // holds P = prop(T1) (algebra folded into Wft)
  u16* h3b = (u16*)alloc((size_t)N * 256 * 2);
  float* bf = (float*)alloc(256 * 4);
  u16* W1t = (u16*)alloc(128 * 128 * 2);
  u16* W2t = (u16*)alloc(128 * 128 * 2);
  u16* Wft = (u16*)alloc(256 * 384 * 2);
  u8* W4t8 = (u8*)alloc(256 * 256);
  float* W56 = (float*)alloc(128 * 256 * 4);
  float* b56 = (float*)alloc(256 * 4);
  float* dis = (float*)alloc((size_t)N * 4);
  float* S1 = (float*)alloc((size_t)G * 256 * 4);
  float* S2 = (float*)alloc((size_t)G * 256 * 4);
  float* S4 = (float*)alloc((size_t)G * 256 * 4);
  float* hc = (float*)alloc((size_t)G * 512 * 4);
  float* mu = (float*)alloc(512 * 4);
  float* rstd = (float*)alloc(512 * 4);
  size_t zoff = off;
  int* deg = (int*)alloc((size_t)N * 4);
  int* indeg = (int*)alloc((size_t)N * 4);
  size_t zlen = off - zoff;
  int* rowptr = (int*)alloc(((size_t)N + 1) * 4);
  int* rowcur = (int*)alloc((size_t)N * 4);
  int* csre = (int*)alloc((size_t)E * 4);
  int* bsum = (int*)alloc(260 * 4);
  int* boff = (int*)alloc(260 * 4);
  if (off > ws_size)
    fprintf(stderr, "WARNING: ws too small: need %zu have %zu\n", off, ws_size);

  hipMemsetAsync(base + zoff, 0, zlen, stream);

  // CSR build
  k_hist<<<(E + 255) / 256, 256, 0, stream>>>(dst, indeg, E);
  int B = (N + 1023) / 1024;  // 98; must be <= 256
  k_scan1<<<B, 256, 0, stream>>>(indeg, rowptr, bsum, N);
  k_scan2<<<1, 256, 0, stream>>>(bsum, boff, B);
  k_scan3<<<B, 256, 0, stream>>>(rowptr, boff, rowcur, N, B);
  k_scatter<<<(E + 255) / 256, 256, 0, stream>>>(src, dst, rowcur, deg, csre, E);

  // weight prep + dis (after scatter's deg histogram)
  k_prep<<<642 + B, 256, 0, stream>>>(chebW, W3, Wft, chebB, b3, bf,
                                      W1, W1t, W2, W2t, W4, W4t8,
                                      W5, W6, b5, b6, W56, b56, deg, dis, N);

  // node MLP fused: T0 = act(act(F@W1+b1)@W2+b2)
  k_gemm12<<<(N + 63) / 64, 256, 0, stream>>>(features, N, W1t, b1, W2t, b2, T0b);

  // propagation via CSR gather (no atomics); both are pure props now
  int ggrid = (N + 3) / 4;
  k_gather<<<ggrid, 256, 0, stream>>>(T0b, rowptr, csre, dis, nullptr, 1.0f, T1b, N);
  k_gather<<<ggrid, 256, 0, stream>>>(T1b, rowptr, csre, dis, nullptr, 1.0f, T2b, N);

  // fused: h3 = act(act([T0|T1|P]@Wft' + bf) @ W4 + b4)
  k_gemm34<<<(N + 63) / 64, 256, 0, stream>>>(T0b, T1b, T2b, N, Wft, bf,
                                              W4t8, b4, h3b);

  // graph-level chains (G=1000, fp32, cheap); W5/W6 folded into W56
  {
    dim3 grid2(256 / 64, (G + 63) / 64, 2);
    k_gemm2w<<<grid2, 256, 0, stream>>>(xlx, G, W8, b8, S1, W56, b56, S4);
    dim3 grid(256 / 64, (G + 63) / 64);
    k_gemm<<<grid, 256, 0, stream>>>(S1, G, 256, W9, 256, b9, 1, S2);
  }

  k_pool<<<G, 256, 0, stream>>>(h3b, S2, S4, 1.0f / (float)npg, hc, npg);
  k_bnstats<<<512, 256, 0, stream>>>(hc, mu, rstd, G);
  k_final<<<G, 256, 0, stream>>>(hc, mu, rstd, gamma, beta, W7, b7, (float*)d_out);
}